// Round 10
// baseline (2725.729 us; speedup 1.0000x reference)
//
#include <hip/hip_runtime.h>
#include <hip/hip_bf16.h>

constexpr int NG   = 8;          // graphs
constexpr int NPG  = 4096;       // nodes per graph
constexpr int NT   = NG * NPG;   // 32768 total nodes
constexpr int NS   = 2048;       // fps samples per graph
constexpr int GS   = NG * NS;    // 16384
constexpr int KN   = 64;         // max neighbors
constexpr int NE   = NG * 65536; // 524288 edges
constexpr int NC   = 13;         // classes
constexpr int NWORK = 248;       // worker blocks in phaseA (blocks 8..255)

__device__ __forceinline__ float inp_val(const float* norm, const float* pos, const float* x,
                                         int node, int dim) {
  if (dim < 3) return norm[(size_t)node * 3 + dim];
  if (dim < 6) return pos[(size_t)node * 3 + (dim - 3)];
  return x[(size_t)node * 2 + (dim - 6)];
}

// agent-scope arrive-and-wait barrier among the NWORK worker blocks
__device__ __forceinline__ void wbar(int* ctrs, int k, int target) {
  __syncthreads();
  __threadfence();
  if (threadIdx.x == 0) {
    __hip_atomic_fetch_add(&ctrs[k], 1, __ATOMIC_RELEASE, __HIP_MEMORY_SCOPE_AGENT);
    while (__hip_atomic_load(&ctrs[k], __ATOMIC_ACQUIRE, __HIP_MEMORY_SCOPE_AGENT) < target)
      __builtin_amdgcn_s_sleep(16);
  }
  __syncthreads();
}

// ---- phase A (cooperative, 256 blocks x 256 thr) ----
// blocks 0-7: fps; flushes qpos/idxf every 64 steps + publishes progress.
// blocks 8-255: feat1+deg1 -> scan -> fill1 -> agg1+feat2 -> agg2 ->
//               pipelined {radius+mapset+pointconv} chunks under fps.
__global__ __launch_bounds__(256, 1) void phaseA_kernel(
    const float* __restrict__ pos, int* __restrict__ idxf, float* __restrict__ qpos,
    const float* __restrict__ norm, const float* __restrict__ x,
    const float* __restrict__ W1, float* __restrict__ t1,
    const int* __restrict__ ei, int* __restrict__ deg,
    int* __restrict__ off1, int* __restrict__ cur1, int* __restrict__ el1,
    const float* __restrict__ b1, const float* __restrict__ W2, float* __restrict__ t2,
    const float* __restrict__ b2, float* __restrict__ h2,
    int* __restrict__ mapv, float* __restrict__ xint,
    int* __restrict__ wctr) {
  __shared__ __align__(16) char smem[115728];
  if (blockIdx.x >= 8) {
    // ================= workers =================
    const int wb = blockIdx.x - 8;
    const int sub = threadIdx.x >> 6;   // 0..3 (one wave each)
    const int f = threadIdx.x & 63;
    float (*wrow)[80] = (float (*)[80])smem;
    int* sscan = (int*)(smem + 1280);
    // stage 0: feat1 (t1 = inp @ W1) + deg1
    for (int n0 = wb * 4; n0 < NT; n0 += NWORK * 4) {
      int n = n0 + sub;
      if (f < 8) wrow[sub][f] = inp_val(norm, pos, x, n, f);
      float acc = 0.f;  // same-wave LDS write->read, lockstep
#pragma unroll
      for (int i = 0; i < 8; ++i) acc += wrow[sub][i] * W1[i * 64 + f];
      t1[(size_t)n * 64 + f] = acc;
    }
    for (int e = wb * 256 + threadIdx.x; e < NE; e += NWORK * 256)
      atomicAdd(&deg[ei[NE + e]], 1);
    wbar(wctr, 0, NWORK);
    // stage 1: exclusive scan deg -> off1 (block 0 only)
    if (wb == 0) {
      int t = threadIdx.x, base = t * 128, s = 0;
      for (int i = 0; i < 128; ++i) s += deg[base + i];
      sscan[t] = s;
      __syncthreads();
      for (int d = 1; d < 256; d <<= 1) {
        int v = (t >= d) ? sscan[t - d] : 0;
        __syncthreads();
        sscan[t] += v;
        __syncthreads();
      }
      int excl = (t == 0) ? 0 : sscan[t - 1];
      for (int i = 0; i < 128; ++i) { off1[base + i] = excl; excl += deg[base + i]; }
      if (t == 255) off1[NT] = sscan[255];
    }
    wbar(wctr, 1, NWORK);
    // stage 2: fill1 (CSR edge lists)
    for (int e = wb * 256 + threadIdx.x; e < NE; e += NWORK * 256) {
      int sN = ei[e], dN = ei[NE + e];
      int p = off1[dN] + atomicAdd(&cur1[dN], 1);
      el1[p] = sN;
    }
    wbar(wctr, 2, NWORK);
    // stage 3: fused agg1 + feat2 (h1 stays in LDS)
    for (int n0 = wb * 4; n0 < NT; n0 += NWORK * 4) {
      int n = n0 + sub;
      int e0 = off1[n], e1 = off1[n + 1];
      float acc = 0.f;
      for (int j = e0; j < e1; ++j) acc += t1[(size_t)el1[j] * 64 + f];
      wrow[sub][f] = fmaxf(acc + b1[f], 0.f);
      if (f < 8) wrow[sub][64 + f] = inp_val(norm, pos, x, n, f);
      float a0 = 0.f, a1 = 0.f;
#pragma unroll 8
      for (int i = 0; i < 72; ++i) {
        float r = wrow[sub][i];
        a0 += r * W2[i * 128 + f];
        a1 += r * W2[i * 128 + 64 + f];
      }
      t2[(size_t)n * 128 + f] = a0;
      t2[(size_t)n * 128 + 64 + f] = a1;
    }
    wbar(wctr, 3, NWORK);
    // stage 4: agg2 (h2 = relu(sum t2 + b2))
    {
      const int f2 = threadIdx.x & 127, sub2 = threadIdx.x >> 7;
      for (int n0 = wb * 2; n0 < NT; n0 += NWORK * 2) {
        int n = n0 + sub2;
        int e0 = off1[n], e1 = off1[n + 1];
        float acc = 0.f;
        for (int j = e0; j < e1; ++j) acc += t2[(size_t)el1[j] * 128 + f2];
        h2[(size_t)n * 128 + f2] = fmaxf(acc + b2[f2], 0.f);
      }
    }
    wbar(wctr, 4, NWORK);  // h2 complete before any pointconv reads it
    // stage 5: pipelined radius + mapset + pointconv over 64 chunks of 256 samples
    {
      float* spx = (float*)smem;
      float* spy = (float*)(smem + 16384);
      float* spz = (float*)(smem + 32768);
      int (*scolsT)[256] = (int (*)[256])(smem + 49152);  // [KN][256]
      int* scnt = (int*)(smem + 114688);
      int* schunk = (int*)(smem + 115712);
      for (;;) {
        if (threadIdx.x == 0)
          *schunk = __hip_atomic_fetch_add(&wctr[8], 1, __ATOMIC_RELAXED,
                                           __HIP_MEMORY_SCOPE_AGENT);
        __syncthreads();
        int chunk = *schunk;
        __syncthreads();
        if (chunk >= 64) break;
        int gC = chunk >> 3, c0 = (chunk & 7) * 256;
        // stage positions of graph gC into LDS
        const float* pgc = pos + (size_t)gC * NPG * 3;
        for (int i = threadIdx.x; i < NPG * 3; i += 256) {
          float v = pgc[i]; int node = i / 3, cc = i - node * 3;
          if (cc == 0) spx[node] = v; else if (cc == 1) spy[node] = v; else spz[node] = v;
        }
        // wait for fps to finish these samples
        if (threadIdx.x == 0) {
          while (__hip_atomic_load(&wctr[16 + gC], __ATOMIC_ACQUIRE,
                                   __HIP_MEMORY_SCOPE_AGENT) < c0 + 256)
            __builtin_amdgcn_s_sleep(32);
        }
        __syncthreads();
        // radius (exact arithmetic, first-K lowest index) + mapset; 1 thread/sample
        {
          int m = gC * NS + c0 + threadIdx.x;
          mapv[idxf[m]] = m;
          float qx = qpos[(size_t)m * 3], qy = qpos[(size_t)m * 3 + 1],
                qz = qpos[(size_t)m * 3 + 2];
          int c = 0;
          for (int i = 0; i < NPG; ++i) {
            float dx = __fsub_rn(spx[i], qx);
            float dy = __fsub_rn(spy[i], qy);
            float dz = __fsub_rn(spz[i], qz);
            float d2 = __fadd_rn(__fadd_rn(__fmul_rn(dx, dx), __fmul_rn(dy, dy)),
                                 __fmul_rn(dz, dz));
            if (d2 < 0.16f) {
              scolsT[c][threadIdx.x] = i;
              if (++c == KN) break;
            }
          }
          scnt[threadIdx.x] = c;
        }
        __syncthreads();
        // pointconv: 4 samples concurrently (64 feature lanes each)
        for (int ss = (threadIdx.x >> 6); ss < 256; ss += 4) {
          int fc = threadIdx.x & 63;
          int m = gC * NS + c0 + ss;
          int n = scnt[ss];
          float m0 = -INFINITY, m1 = -INFINITY, mpv = -INFINITY;
          for (int k = 0; k < n; ++k) {
            int cc = scolsT[k][ss];
            size_t b = (size_t)(gC * NPG + cc);
            m0 = fmaxf(m0, h2[b * 128 + fc]);
            m1 = fmaxf(m1, h2[b * 128 + 64 + fc]);
            if (fc < 3) mpv = fmaxf(mpv, (fc == 0 ? spx[cc] : (fc == 1 ? spy[cc] : spz[cc])));
          }
          float* xo = xint + (size_t)m * 131;
          xo[fc] = m0;
          xo[64 + fc] = m1;
          if (fc < 3) xo[128 + fc] = __fsub_rn(mpv, qpos[(size_t)m * 3 + fc]);
        }
        __syncthreads();  // before next chunk restages spx
      }
    }
    return;
  }
  // ================= FPS (round-7 arithmetic; batched flush + progress) =================
  const int g = blockIdx.x;
  float4* qrec = (float4*)smem;                 // [NS] 32 KB
  int* irec = (int*)(smem + 32768);             // [NS] 8 KB
  float4 (*sq)[4] = (float4 (*)[4])(smem + 40960);
  int (*sidx)[4] = (int (*)[4])(smem + 41088);
  const float* pg = pos + (size_t)g * NPG * 3;
  const int tid = threadIdx.x;
  const int wave = tid >> 6, lane = tid & 63;
  const int p0 = tid * 16;

  float a[48];
  {
    const float4* pg4 = reinterpret_cast<const float4*>(pg + (size_t)p0 * 3);
#pragma unroll
    for (int j = 0; j < 12; ++j) {
      float4 t = pg4[j];
      a[4 * j + 0] = t.x; a[4 * j + 1] = t.y; a[4 * j + 2] = t.z; a[4 * j + 3] = t.w;
    }
  }
  float px[16], py[16], pz[16], mind[16];
#pragma unroll
  for (int i = 0; i < 16; ++i) {
    px[i] = a[3 * i]; py[i] = a[3 * i + 1]; pz[i] = a[3 * i + 2];
    mind[i] = __int_as_float(0x7f800000);  // +inf
  }
  float cx = pg[0], cy = pg[1], cz = pg[2];
  int idx_sel = 0;  // maintained by tid 0

  for (int s = 0; s < NS; ++s) {
    if (tid == 0) { irec[s] = idx_sel; qrec[s] = make_float4(cx, cy, cz, 0.f); }
    float bestv = -1.f, bx = 0.f, by = 0.f, bz = 0.f;
    int bi = 0;
#pragma unroll
    for (int i = 0; i < 16; ++i) {
      float dx = __fsub_rn(px[i], cx);
      float dy = __fsub_rn(py[i], cy);
      float dz = __fsub_rn(pz[i], cz);
      float dd = __fadd_rn(__fadd_rn(__fmul_rn(dx, dx), __fmul_rn(dy, dy)), __fmul_rn(dz, dz));
      float nm = fminf(mind[i], dd);
      mind[i] = nm;
      bool gt = nm > bestv;   // strict > keeps first occurrence
      bestv = gt ? nm : bestv;
      bx = gt ? px[i] : bx;
      by = gt ? py[i] : by;
      bz = gt ? pz[i] : bz;
      bi = gt ? i : bi;
    }
    float v = bestv;
    v = fmaxf(v, __int_as_float(__builtin_amdgcn_update_dpp(0, __float_as_int(v), 0x111, 0xF, 0xF, true)));
    v = fmaxf(v, __int_as_float(__builtin_amdgcn_update_dpp(0, __float_as_int(v), 0x112, 0xF, 0xF, true)));
    v = fmaxf(v, __int_as_float(__builtin_amdgcn_update_dpp(0, __float_as_int(v), 0x114, 0xF, 0xF, true)));
    v = fmaxf(v, __int_as_float(__builtin_amdgcn_update_dpp(0, __float_as_int(v), 0x118, 0xF, 0xF, true)));
    v = fmaxf(v, __int_as_float(__builtin_amdgcn_update_dpp(0, __float_as_int(v), 0x142, 0xF, 0xF, true)));
    v = fmaxf(v, __int_as_float(__builtin_amdgcn_update_dpp(0, __float_as_int(v), 0x143, 0xF, 0xF, true)));
    int maxbits = __builtin_amdgcn_readlane(__float_as_int(v), 63);
    float wavemax = __int_as_float(maxbits);
    unsigned long long ball = __ballot(bestv == wavemax);
    int winner = __ffsll(ball) - 1;  // lowest lane = lowest index (contiguous ownership)
    int b = s & 1;
    if (lane == winner) {
      sq[b][wave] = make_float4(bx, by, bz, wavemax);
      sidx[b][wave] = p0 + bi;
    }
    __syncthreads();
    float4 q0 = sq[b][0], q1 = sq[b][1], q2 = sq[b][2], q3 = sq[b][3];
    float4 qs = q3;
    if (q2.w >= qs.w) qs = q2;   // >= toward lower wave = lowest index on ties
    if (q1.w >= qs.w) qs = q1;
    if (q0.w >= qs.w) qs = q0;
    cx = qs.x; cy = qs.y; cz = qs.z;
    if (tid == 0) {  // resolve record index off the critical path
      int i0 = sidx[b][0], i1 = sidx[b][1], i2 = sidx[b][2], i3 = sidx[b][3];
      float r = q3.w; int is = i3;
      if (q2.w >= r) { r = q2.w; is = i2; }
      if (q1.w >= r) { r = q1.w; is = i1; }
      if (q0.w >= r) { r = q0.w; is = i0; }
      idx_sel = is;
    }
    // batched flush of the last 64 records + progress publish
    if ((s & 63) == 63) {
      int smp = (s - 63) + (tid >> 2);
      int comp = tid & 3;
      if (comp < 3) qpos[(size_t)(g * NS + smp) * 3 + comp] = ((float*)&qrec[smp])[comp];
      else idxf[g * NS + smp] = g * NPG + irec[smp];
      __threadfence();
      __syncthreads();
      if (tid == 0)
        __hip_atomic_store(&wctr[16 + g], s + 1, __ATOMIC_RELEASE, __HIP_MEMORY_SCOPE_AGENT);
    }
  }
}

// feat3 (blocks 0..GS-1) fused with deg2 (blocks GS..GS+NE/256-1)
__global__ void featdeg_kernel(const float* __restrict__ xint, const int* __restrict__ idxf,
                               const float* __restrict__ norm, const float* __restrict__ pos,
                               const float* __restrict__ x, const float* __restrict__ W3,
                               float* __restrict__ t3,
                               const int* __restrict__ ei, const int* __restrict__ mp,
                               int* __restrict__ deg) {
  if (blockIdx.x >= GS) {
    int e = (blockIdx.x - GS) * 256 + threadIdx.x;  // exactly NE threads
    int ns = mp[ei[e]], nd = mp[ei[NE + e]];
    if (ns >= 0 && nd >= 0) atomicAdd(&deg[nd], 1);
    return;
  }
  int m = blockIdx.x, f = threadIdx.x;  // 256 threads
  __shared__ float row[139];
  if (f < 131) row[f] = xint[(size_t)m * 131 + f];
  else if (f < 139) { int node = idxf[m]; row[f] = inp_val(norm, pos, x, node, f - 131); }
  __syncthreads();
  float acc = 0.f;
#pragma unroll 8
  for (int i = 0; i < 139; ++i) acc += row[i] * W3[i * 256 + f];
  t3[(size_t)m * 256 + f] = acc;
}

__global__ void fill2_kernel(const int* __restrict__ ei, const int* __restrict__ mp,
                             const int* __restrict__ off, int* __restrict__ cur,
                             int* __restrict__ el) {
  int e = blockIdx.x * 256 + threadIdx.x;
  if (e < NE) {
    int ns = mp[ei[e]], nd = mp[ei[NE + e]];
    if (ns >= 0 && nd >= 0) {
      int p = off[nd] + atomicAdd(&cur[nd], 1);
      el[p] = ns;
    }
  }
}

// single-block exclusive scan, n <= 32768, writes out[0..n]
__global__ __launch_bounds__(1024) void scan_kernel(const int* __restrict__ in,
                                                    int* __restrict__ out, int n) {
  __shared__ int ls[1024];
  int tid = threadIdx.x;
  int per = (n + 1023) >> 10;
  int base = tid * per;
  int s = 0;
  for (int i = 0; i < per; ++i) { int idx = base + i; if (idx < n) s += in[idx]; }
  ls[tid] = s;
  __syncthreads();
  for (int d = 1; d < 1024; d <<= 1) {
    int v = (tid >= d) ? ls[tid - d] : 0;
    __syncthreads();
    ls[tid] += v;
    __syncthreads();
  }
  int excl = (tid == 0) ? 0 : ls[tid - 1];
  for (int i = 0; i < per; ++i) {
    int idx = base + i;
    if (idx < n) { out[idx] = excl; excl += in[idx]; }
  }
  if (tid == 1023) out[n] = ls[1023];
}

// gather-side GCN aggregation: out[node,f] = relu(b[f] + sum_{src in list} t[src,f])
__global__ void agg_kernel(const float* __restrict__ t, const int* __restrict__ off,
                           const int* __restrict__ el, const float* __restrict__ b,
                           float* __restrict__ out, int F) {
  int node = blockIdx.x, f = threadIdx.x;
  int e0 = off[node], e1 = off[node + 1];
  float acc = 0.f;
  for (int j = e0; j < e1; ++j) acc += t[(size_t)el[j] * F + f];
  out[(size_t)node * F + f] = fmaxf(acc + b[f], 0.f);
}

// ---------------- pooling + head ----------------
__global__ void pool_kernel(const float* __restrict__ h3, float* __restrict__ pooled) {
  int g = blockIdx.x, ch = blockIdx.y, f = threadIdx.x;  // 256 threads
  float mx = 0.f;  // h3 >= 0 (relu)
  size_t base = ((size_t)g * NS + (size_t)ch * 256) * 256 + f;
  for (int s = 0; s < 256; ++s) mx = fmaxf(mx, h3[base + (size_t)s * 256]);
  atomicMax((int*)pooled + g * 256 + f, __float_as_int(mx));
}

__global__ void head_kernel(const float* __restrict__ pooled, const float* __restrict__ lw,
                            const float* __restrict__ lb, float* __restrict__ outp) {
  __shared__ float lg[NG * NC];
  int t = threadIdx.x;  // 128 threads
  if (t < NG * NC) {
    int g = t / NC, c = t % NC;
    float acc = lb[c];
    for (int k = 0; k < 256; ++k) acc += pooled[g * 256 + k] * lw[k * NC + c];
    lg[t] = acc;
  }
  __syncthreads();
  if (t < NG) {
    int g = t;
    float mx = -INFINITY;
    for (int c = 0; c < NC; ++c) mx = fmaxf(mx, lg[g * NC + c]);
    float sum = 0.f;
    for (int c = 0; c < NC; ++c) sum += expf(lg[g * NC + c] - mx);
    float lse = logf(sum);
    float ov[NC];
    float mx2 = -INFINITY;
    for (int c = 0; c < NC; ++c) {
      ov[c] = lg[g * NC + c] - mx - lse;
      outp[g * NC + c] = ov[c];
      mx2 = fmaxf(mx2, ov[c]);
    }
    float s2 = 0.f;
    for (int c = 0; c < NC; ++c) s2 += expf(ov[c] - mx2);
    for (int c = 0; c < NC; ++c) outp[NG * NC + g * NC + c] = expf(ov[c] - mx2) / s2;
  }
}

extern "C" void kernel_launch(void* const* d_in, const int* in_sizes, int n_in,
                              void* d_out, int out_size, void* d_ws, size_t ws_size,
                              hipStream_t stream) {
  const float* norm = (const float*)d_in[0];
  const float* pos  = (const float*)d_in[1];
  const float* x    = (const float*)d_in[2];
  const int* ei     = (const int*)d_in[3];   // int32! row0 = src, row1 = dst
  // d_in[4] = batch (int32, unused)
  const float* W1 = (const float*)d_in[5];
  const float* b1 = (const float*)d_in[6];
  const float* W2 = (const float*)d_in[7];
  const float* b2 = (const float*)d_in[8];
  const float* W3 = (const float*)d_in[9];
  const float* b3 = (const float*)d_in[10];
  const float* lw = (const float*)d_in[11];
  const float* lb = (const float*)d_in[12];
  float* outp = (float*)d_out;

  char* w = (char*)d_ws;
  size_t o = 0;
  auto alloc = [&](size_t bytes) -> void* {
    void* p = w + o;
    o = (o + bytes + 255) & ~(size_t)255;
    return p;
  };
  float* A    = (float*)alloc((size_t)NT * 128 * 4);  // t2 -> t3
  float* Bf   = (float*)alloc((size_t)NT * 128 * 4);  // h2 -> h3
  float* T1   = (float*)alloc((size_t)NT * 64 * 4);   // t1
  float* xint = (float*)alloc((size_t)GS * 131 * 4);
  int* deg1   = (int*)alloc((size_t)NT * 4);
  int* off1   = (int*)alloc((size_t)(NT + 1) * 4);
  int* cur1   = (int*)alloc((size_t)NT * 4);
  int* el1    = (int*)alloc((size_t)NE * 4);
  int* deg2   = (int*)alloc((size_t)GS * 4);
  int* off2   = (int*)alloc((size_t)(GS + 1) * 4);
  int* cur2   = (int*)alloc((size_t)GS * 4);
  int* el2    = (int*)alloc((size_t)NE * 4);
  int* idxf   = (int*)alloc((size_t)GS * 4);
  float* qpos = (float*)alloc((size_t)GS * 3 * 4);
  int* mapv   = (int*)alloc((size_t)NT * 4);
  float* pooled = (float*)alloc((size_t)NG * 256 * 4);
  int* wctr   = (int*)alloc(128);

  hipMemsetAsync(deg1, 0, (size_t)NT * 4, stream);
  hipMemsetAsync(cur1, 0, (size_t)NT * 4, stream);
  hipMemsetAsync(deg2, 0, (size_t)GS * 4, stream);
  hipMemsetAsync(cur2, 0, (size_t)GS * 4, stream);
  hipMemsetAsync(mapv, 0xFF, (size_t)NT * 4, stream);  // -1
  hipMemsetAsync(pooled, 0, (size_t)NG * 256 * 4, stream);
  hipMemsetAsync(wctr, 0, 128, stream);

  // phase A (cooperative): fps ∥ {GCN layers 1-2, then radius+mapset+pointconv chunks}
  {
    void* ka[] = {(void*)&pos, (void*)&idxf, (void*)&qpos, (void*)&norm, (void*)&x,
                  (void*)&W1, (void*)&T1, (void*)&ei, (void*)&deg1,
                  (void*)&off1, (void*)&cur1, (void*)&el1,
                  (void*)&b1, (void*)&W2, (void*)&A, (void*)&b2, (void*)&Bf,
                  (void*)&mapv, (void*)&xint, (void*)&wctr};
    hipLaunchCooperativeKernel((const void*)phaseA_kernel, dim3(8 + NWORK), dim3(256),
                               ka, 0, stream);
  }
  // feat3 + deg2 fused
  featdeg_kernel<<<GS + NE / 256, 256, 0, stream>>>(xint, idxf, norm, pos, x, W3, A,
                                                    ei, mapv, deg2);
  scan_kernel<<<1, 1024, 0, stream>>>(deg2, off2, GS);
  fill2_kernel<<<NE / 256, 256, 0, stream>>>(ei, mapv, off2, cur2, el2);
  // layer 3
  agg_kernel<<<GS, 256, 0, stream>>>(A, off2, el2, b3, Bf, 256);
  // pool + head
  pool_kernel<<<dim3(NG, NS / 256), 256, 0, stream>>>(Bf, pooled);
  head_kernel<<<1, 128, 0, stream>>>(pooled, lw, lb, outp);
}

// Round 11
// 2489.584 us; speedup vs baseline: 1.0949x; 1.0949x over previous
//
#include <hip/hip_runtime.h>
#include <hip/hip_bf16.h>

constexpr int NG   = 8;          // graphs
constexpr int NPG  = 4096;       // nodes per graph
constexpr int NT   = NG * NPG;   // 32768 total nodes
constexpr int NS   = 2048;       // fps samples per graph
constexpr int GS   = NG * NS;    // 16384
constexpr int KN   = 64;         // max neighbors
constexpr int NE   = NG * 65536; // 524288 edges
constexpr int NC   = 13;         // classes
constexpr int NWORK = 248;       // worker blocks in phaseA (blocks 8..255)
constexpr int NF3B = 4096;       // feat3 blocks in post2 (4 samples each)

__device__ __forceinline__ float inp_val(const float* norm, const float* pos, const float* x,
                                         int node, int dim) {
  if (dim < 3) return norm[(size_t)node * 3 + dim];
  if (dim < 6) return pos[(size_t)node * 3 + (dim - 3)];
  return x[(size_t)node * 2 + (dim - 6)];
}

// agent-scope arrive-and-wait barrier among the NWORK worker blocks
__device__ __forceinline__ void wbar(int* ctrs, int k, int target) {
  __syncthreads();
  __threadfence();
  if (threadIdx.x == 0) {
    __hip_atomic_fetch_add(&ctrs[k], 1, __ATOMIC_RELEASE, __HIP_MEMORY_SCOPE_AGENT);
    while (__hip_atomic_load(&ctrs[k], __ATOMIC_ACQUIRE, __HIP_MEMORY_SCOPE_AGENT) < target)
      __builtin_amdgcn_s_sleep(16);
  }
  __syncthreads();
}

// ---- phase A (cooperative, 256 blocks x 256 thr) — EXACT round-9 structure ----
// blocks 0-7: fps. blocks 8-255: feat1+deg1 -> scan -> fill1 -> agg1+feat2 -> agg2, then exit.
__global__ __launch_bounds__(256, 1) void phaseA_kernel(
    const float* __restrict__ pos, int* __restrict__ idxf, float* __restrict__ qpos,
    const float* __restrict__ norm, const float* __restrict__ x,
    const float* __restrict__ W1, float* __restrict__ t1,
    const int* __restrict__ ei, int* __restrict__ deg,
    int* __restrict__ off1, int* __restrict__ cur1, int* __restrict__ el1,
    const float* __restrict__ b1, const float* __restrict__ W2, float* __restrict__ t2,
    const float* __restrict__ b2, float* __restrict__ h2,
    int* __restrict__ wctr) {
  if (blockIdx.x >= 8) {
    // ================= workers =================
    const int wb = blockIdx.x - 8;
    const int sub = threadIdx.x >> 6;   // 0..3 (one wave each)
    const int f = threadIdx.x & 63;
    __shared__ float wrow[4][80];
    __shared__ int sscan[256];
    // stage 0: feat1 (t1 = inp @ W1) + deg1
    for (int n0 = wb * 4; n0 < NT; n0 += NWORK * 4) {
      int n = n0 + sub;
      if (f < 8) wrow[sub][f] = inp_val(norm, pos, x, n, f);
      float acc = 0.f;  // same-wave LDS write->read, lockstep
#pragma unroll
      for (int i = 0; i < 8; ++i) acc += wrow[sub][i] * W1[i * 64 + f];
      t1[(size_t)n * 64 + f] = acc;
    }
    for (int e = wb * 256 + threadIdx.x; e < NE; e += NWORK * 256)
      atomicAdd(&deg[ei[NE + e]], 1);
    wbar(wctr, 0, NWORK);
    // stage 1: exclusive scan deg -> off1 (block 0 only)
    if (wb == 0) {
      int t = threadIdx.x, base = t * 128, s = 0;
      for (int i = 0; i < 128; ++i) s += deg[base + i];
      sscan[t] = s;
      __syncthreads();
      for (int d = 1; d < 256; d <<= 1) {
        int v = (t >= d) ? sscan[t - d] : 0;
        __syncthreads();
        sscan[t] += v;
        __syncthreads();
      }
      int excl = (t == 0) ? 0 : sscan[t - 1];
      for (int i = 0; i < 128; ++i) { off1[base + i] = excl; excl += deg[base + i]; }
      if (t == 255) off1[NT] = sscan[255];
    }
    wbar(wctr, 1, NWORK);
    // stage 2: fill1 (CSR edge lists)
    for (int e = wb * 256 + threadIdx.x; e < NE; e += NWORK * 256) {
      int sN = ei[e], dN = ei[NE + e];
      int p = off1[dN] + atomicAdd(&cur1[dN], 1);
      el1[p] = sN;
    }
    wbar(wctr, 2, NWORK);
    // stage 3: fused agg1 + feat2 (h1 stays in LDS)
    for (int n0 = wb * 4; n0 < NT; n0 += NWORK * 4) {
      int n = n0 + sub;
      int e0 = off1[n], e1 = off1[n + 1];
      float acc = 0.f;
      for (int j = e0; j < e1; ++j) acc += t1[(size_t)el1[j] * 64 + f];
      wrow[sub][f] = fmaxf(acc + b1[f], 0.f);
      if (f < 8) wrow[sub][64 + f] = inp_val(norm, pos, x, n, f);
      float a0 = 0.f, a1 = 0.f;
#pragma unroll 8
      for (int i = 0; i < 72; ++i) {
        float r = wrow[sub][i];
        a0 += r * W2[i * 128 + f];
        a1 += r * W2[i * 128 + 64 + f];
      }
      t2[(size_t)n * 128 + f] = a0;
      t2[(size_t)n * 128 + 64 + f] = a1;
    }
    wbar(wctr, 3, NWORK);
    // stage 4: agg2 (h2 = relu(sum t2 + b2)); then exit -> chip quiet for fps
    {
      const int f2 = threadIdx.x & 127, sub2 = threadIdx.x >> 7;
      for (int n0 = wb * 2; n0 < NT; n0 += NWORK * 2) {
        int n = n0 + sub2;
        int e0 = off1[n], e1 = off1[n + 1];
        float acc = 0.f;
        for (int j = e0; j < e1; ++j) acc += t2[(size_t)el1[j] * 128 + f2];
        h2[(size_t)n * 128 + f2] = fmaxf(acc + b2[f2], 0.f);
      }
    }
    return;
  }
  // ================= FPS (round-7/9 arithmetic, bulk write at end) =================
  const int g = blockIdx.x;
  __shared__ float4 sq[2][4];
  __shared__ int sidx[2][4];
  __shared__ float4 qrec[NS];  // 32 KB
  __shared__ int irec[NS];     // 8 KB
  const float* pg = pos + (size_t)g * NPG * 3;
  const int tid = threadIdx.x;
  const int wave = tid >> 6, lane = tid & 63;
  const int p0 = tid * 16;

  float a[48];
  {
    const float4* pg4 = reinterpret_cast<const float4*>(pg + (size_t)p0 * 3);
#pragma unroll
    for (int j = 0; j < 12; ++j) {
      float4 t = pg4[j];
      a[4 * j + 0] = t.x; a[4 * j + 1] = t.y; a[4 * j + 2] = t.z; a[4 * j + 3] = t.w;
    }
  }
  float px[16], py[16], pz[16], mind[16];
#pragma unroll
  for (int i = 0; i < 16; ++i) {
    px[i] = a[3 * i]; py[i] = a[3 * i + 1]; pz[i] = a[3 * i + 2];
    mind[i] = __int_as_float(0x7f800000);  // +inf
  }
  float cx = pg[0], cy = pg[1], cz = pg[2];
  int idx_sel = 0;  // maintained by tid 0

  for (int s = 0; s < NS; ++s) {
    if (tid == 0) { irec[s] = idx_sel; qrec[s] = make_float4(cx, cy, cz, 0.f); }
    float bestv = -1.f, bx = 0.f, by = 0.f, bz = 0.f;
    int bi = 0;
#pragma unroll
    for (int i = 0; i < 16; ++i) {
      float dx = __fsub_rn(px[i], cx);
      float dy = __fsub_rn(py[i], cy);
      float dz = __fsub_rn(pz[i], cz);
      float dd = __fadd_rn(__fadd_rn(__fmul_rn(dx, dx), __fmul_rn(dy, dy)), __fmul_rn(dz, dz));
      float nm = fminf(mind[i], dd);
      mind[i] = nm;
      bool gt = nm > bestv;   // strict > keeps first occurrence
      bestv = gt ? nm : bestv;
      bx = gt ? px[i] : bx;
      by = gt ? py[i] : by;
      bz = gt ? pz[i] : bz;
      bi = gt ? i : bi;
    }
    float v = bestv;
    v = fmaxf(v, __int_as_float(__builtin_amdgcn_update_dpp(0, __float_as_int(v), 0x111, 0xF, 0xF, true)));
    v = fmaxf(v, __int_as_float(__builtin_amdgcn_update_dpp(0, __float_as_int(v), 0x112, 0xF, 0xF, true)));
    v = fmaxf(v, __int_as_float(__builtin_amdgcn_update_dpp(0, __float_as_int(v), 0x114, 0xF, 0xF, true)));
    v = fmaxf(v, __int_as_float(__builtin_amdgcn_update_dpp(0, __float_as_int(v), 0x118, 0xF, 0xF, true)));
    v = fmaxf(v, __int_as_float(__builtin_amdgcn_update_dpp(0, __float_as_int(v), 0x142, 0xF, 0xF, true)));
    v = fmaxf(v, __int_as_float(__builtin_amdgcn_update_dpp(0, __float_as_int(v), 0x143, 0xF, 0xF, true)));
    int maxbits = __builtin_amdgcn_readlane(__float_as_int(v), 63);
    float wavemax = __int_as_float(maxbits);
    unsigned long long ball = __ballot(bestv == wavemax);
    int winner = __ffsll(ball) - 1;  // lowest lane = lowest index (contiguous ownership)
    int b = s & 1;
    if (lane == winner) {
      sq[b][wave] = make_float4(bx, by, bz, wavemax);
      sidx[b][wave] = p0 + bi;
    }
    __syncthreads();
    float4 q0 = sq[b][0], q1 = sq[b][1], q2 = sq[b][2], q3 = sq[b][3];
    float4 qs = q3;
    if (q2.w >= qs.w) qs = q2;   // >= toward lower wave = lowest index on ties
    if (q1.w >= qs.w) qs = q1;
    if (q0.w >= qs.w) qs = q0;
    cx = qs.x; cy = qs.y; cz = qs.z;
    if (tid == 0) {  // resolve record index off the critical path
      int i0 = sidx[b][0], i1 = sidx[b][1], i2 = sidx[b][2], i3 = sidx[b][3];
      float r = q3.w; int is = i3;
      if (q2.w >= r) { r = q2.w; is = i2; }
      if (q1.w >= r) { r = q1.w; is = i1; }
      if (q0.w >= r) { r = q0.w; is = i0; }
      idx_sel = is;
    }
  }
  __syncthreads();
  for (int j = tid; j < NS; j += 256) {
    idxf[g * NS + j] = g * NPG + irec[j];
    float4 q = qrec[j];
    size_t m = (size_t)(g * NS + j) * 3;
    qpos[m + 0] = q.x; qpos[m + 1] = q.y; qpos[m + 2] = q.z;
  }
}

// ---- post1: radius + mapset + pointconv fused (64 blocks x 256 thr) ----
__global__ __launch_bounds__(256, 1) void post1_kernel(
    const float* __restrict__ pos, const float* __restrict__ qpos,
    const int* __restrict__ idxf, const float* __restrict__ h2,
    int* __restrict__ mapv, float* __restrict__ xint) {
  __shared__ float spx[NPG], spy[NPG], spz[NPG];  // 48 KB
  __shared__ int scolsT[KN][256];                 // 64 KB (conflict-free: [k][sample])
  __shared__ int scnt[256];
  const int g = blockIdx.x >> 3;
  const int c0 = (blockIdx.x & 7) * 256;
  const float* pgc = pos + (size_t)g * NPG * 3;
  for (int i = threadIdx.x; i < NPG * 3; i += 256) {
    float v = pgc[i]; int node = i / 3, cc = i - node * 3;
    if (cc == 0) spx[node] = v; else if (cc == 1) spy[node] = v; else spz[node] = v;
  }
  __syncthreads();
  // radius (exact fp32, first-K lowest index) + mapset; 1 thread/sample
  {
    int m = g * NS + c0 + threadIdx.x;
    mapv[idxf[m]] = m;
    float qx = qpos[(size_t)m * 3], qy = qpos[(size_t)m * 3 + 1], qz = qpos[(size_t)m * 3 + 2];
    int c = 0;
    for (int i = 0; i < NPG; ++i) {
      float dx = __fsub_rn(spx[i], qx);
      float dy = __fsub_rn(spy[i], qy);
      float dz = __fsub_rn(spz[i], qz);
      float d2 = __fadd_rn(__fadd_rn(__fmul_rn(dx, dx), __fmul_rn(dy, dy)), __fmul_rn(dz, dz));
      if (d2 < 0.16f) {
        scolsT[c][threadIdx.x] = i;
        if (++c == KN) break;
      }
    }
    scnt[threadIdx.x] = c;
  }
  __syncthreads();
  // pointconv: 4 samples concurrently (64 feature lanes each)
  for (int ss = (threadIdx.x >> 6); ss < 256; ss += 4) {
    int fc = threadIdx.x & 63;
    int m = g * NS + c0 + ss;
    int n = scnt[ss];
    float m0 = -INFINITY, m1 = -INFINITY, mpv = -INFINITY;
    for (int k = 0; k < n; ++k) {
      int cc = scolsT[k][ss];
      size_t b = (size_t)(g * NPG + cc);
      m0 = fmaxf(m0, h2[b * 128 + fc]);
      m1 = fmaxf(m1, h2[b * 128 + 64 + fc]);
      if (fc < 3) mpv = fmaxf(mpv, (fc == 0 ? spx[cc] : (fc == 1 ? spy[cc] : spz[cc])));
    }
    float* xo = xint + (size_t)m * 131;
    xo[fc] = m0;
    xo[64 + fc] = m1;
    if (fc < 3) xo[128 + fc] = __fsub_rn(mpv, qpos[(size_t)m * 3 + fc]);
  }
}

// ---- post2: feat3 (4 samples/block, blocks 0..NF3B-1) + deg2 (blocks NF3B..) ----
__global__ void post2_kernel(const float* __restrict__ xint, const int* __restrict__ idxf,
                             const float* __restrict__ norm, const float* __restrict__ pos,
                             const float* __restrict__ x, const float* __restrict__ W3,
                             float* __restrict__ t3,
                             const int* __restrict__ ei, const int* __restrict__ mp,
                             int* __restrict__ deg) {
  if (blockIdx.x >= NF3B) {
    int e = (blockIdx.x - NF3B) * 256 + threadIdx.x;  // exactly NE threads
    int ns = mp[ei[e]], nd = mp[ei[NE + e]];
    if (ns >= 0 && nd >= 0) atomicAdd(&deg[nd], 1);
    return;
  }
  __shared__ float srow[4][140];
  const int m0 = blockIdx.x * 4;
  for (int j = threadIdx.x; j < 4 * 139; j += 256) {
    int sub = j / 139, i = j - sub * 139;
    int m = m0 + sub;
    srow[sub][i] = (i < 131) ? xint[(size_t)m * 131 + i]
                             : inp_val(norm, pos, x, idxf[m], i - 131);
  }
  __syncthreads();
  int f = threadIdx.x;
  float a0 = 0.f, a1 = 0.f, a2 = 0.f, a3 = 0.f;
#pragma unroll 8
  for (int i = 0; i < 139; ++i) {
    float wv = W3[i * 256 + f];
    a0 += srow[0][i] * wv;
    a1 += srow[1][i] * wv;
    a2 += srow[2][i] * wv;
    a3 += srow[3][i] * wv;
  }
  t3[(size_t)(m0 + 0) * 256 + f] = a0;
  t3[(size_t)(m0 + 1) * 256 + f] = a1;
  t3[(size_t)(m0 + 2) * 256 + f] = a2;
  t3[(size_t)(m0 + 3) * 256 + f] = a3;
}

__global__ void fill2_kernel(const int* __restrict__ ei, const int* __restrict__ mp,
                             const int* __restrict__ off, int* __restrict__ cur,
                             int* __restrict__ el) {
  int e = blockIdx.x * 256 + threadIdx.x;
  if (e < NE) {
    int ns = mp[ei[e]], nd = mp[ei[NE + e]];
    if (ns >= 0 && nd >= 0) {
      int p = off[nd] + atomicAdd(&cur[nd], 1);
      el[p] = ns;
    }
  }
}

// single-block exclusive scan, n <= 32768, writes out[0..n]
__global__ __launch_bounds__(1024) void scan_kernel(const int* __restrict__ in,
                                                    int* __restrict__ out, int n) {
  __shared__ int ls[1024];
  int tid = threadIdx.x;
  int per = (n + 1023) >> 10;
  int base = tid * per;
  int s = 0;
  for (int i = 0; i < per; ++i) { int idx = base + i; if (idx < n) s += in[idx]; }
  ls[tid] = s;
  __syncthreads();
  for (int d = 1; d < 1024; d <<= 1) {
    int v = (tid >= d) ? ls[tid - d] : 0;
    __syncthreads();
    ls[tid] += v;
    __syncthreads();
  }
  int excl = (tid == 0) ? 0 : ls[tid - 1];
  for (int i = 0; i < per; ++i) {
    int idx = base + i;
    if (idx < n) { out[idx] = excl; excl += in[idx]; }
  }
  if (tid == 1023) out[n] = ls[1023];
}

// gather-side GCN aggregation: out[node,f] = relu(b[f] + sum_{src in list} t[src,f])
__global__ void agg_kernel(const float* __restrict__ t, const int* __restrict__ off,
                           const int* __restrict__ el, const float* __restrict__ b,
                           float* __restrict__ out, int F) {
  int node = blockIdx.x, f = threadIdx.x;
  int e0 = off[node], e1 = off[node + 1];
  float acc = 0.f;
  for (int j = e0; j < e1; ++j) acc += t[(size_t)el[j] * F + f];
  out[(size_t)node * F + f] = fmaxf(acc + b[f], 0.f);
}

// ---------------- pooling + head ----------------
__global__ void pool_kernel(const float* __restrict__ h3, float* __restrict__ pooled) {
  int g = blockIdx.x, ch = blockIdx.y, f = threadIdx.x;  // 256 threads
  float mx = 0.f;  // h3 >= 0 (relu)
  size_t base = ((size_t)g * NS + (size_t)ch * 256) * 256 + f;
  for (int s = 0; s < 256; ++s) mx = fmaxf(mx, h3[base + (size_t)s * 256]);
  atomicMax((int*)pooled + g * 256 + f, __float_as_int(mx));
}

__global__ void head_kernel(const float* __restrict__ pooled, const float* __restrict__ lw,
                            const float* __restrict__ lb, float* __restrict__ outp) {
  __shared__ float lg[NG * NC];
  int t = threadIdx.x;  // 128 threads
  if (t < NG * NC) {
    int g = t / NC, c = t % NC;
    float acc = lb[c];
    for (int k = 0; k < 256; ++k) acc += pooled[g * 256 + k] * lw[k * NC + c];
    lg[t] = acc;
  }
  __syncthreads();
  if (t < NG) {
    int g = t;
    float mx = -INFINITY;
    for (int c = 0; c < NC; ++c) mx = fmaxf(mx, lg[g * NC + c]);
    float sum = 0.f;
    for (int c = 0; c < NC; ++c) sum += expf(lg[g * NC + c] - mx);
    float lse = logf(sum);
    float ov[NC];
    float mx2 = -INFINITY;
    for (int c = 0; c < NC; ++c) {
      ov[c] = lg[g * NC + c] - mx - lse;
      outp[g * NC + c] = ov[c];
      mx2 = fmaxf(mx2, ov[c]);
    }
    float s2 = 0.f;
    for (int c = 0; c < NC; ++c) s2 += expf(ov[c] - mx2);
    for (int c = 0; c < NC; ++c) outp[NG * NC + g * NC + c] = expf(ov[c] - mx2) / s2;
  }
}

extern "C" void kernel_launch(void* const* d_in, const int* in_sizes, int n_in,
                              void* d_out, int out_size, void* d_ws, size_t ws_size,
                              hipStream_t stream) {
  const float* norm = (const float*)d_in[0];
  const float* pos  = (const float*)d_in[1];
  const float* x    = (const float*)d_in[2];
  const int* ei     = (const int*)d_in[3];   // int32! row0 = src, row1 = dst
  // d_in[4] = batch (int32, unused)
  const float* W1 = (const float*)d_in[5];
  const float* b1 = (const float*)d_in[6];
  const float* W2 = (const float*)d_in[7];
  const float* b2 = (const float*)d_in[8];
  const float* W3 = (const float*)d_in[9];
  const float* b3 = (const float*)d_in[10];
  const float* lw = (const float*)d_in[11];
  const float* lb = (const float*)d_in[12];
  float* outp = (float*)d_out;

  char* w = (char*)d_ws;
  size_t o = 0;
  auto alloc = [&](size_t bytes) -> void* {
    void* p = w + o;
    o = (o + bytes + 255) & ~(size_t)255;
    return p;
  };
  float* A    = (float*)alloc((size_t)NT * 128 * 4);  // t2 -> t3
  float* Bf   = (float*)alloc((size_t)NT * 128 * 4);  // h2 -> h3
  float* T1   = (float*)alloc((size_t)NT * 64 * 4);   // t1
  float* xint = (float*)alloc((size_t)GS * 131 * 4);
  int* deg1   = (int*)alloc((size_t)NT * 4);
  int* off1   = (int*)alloc((size_t)(NT + 1) * 4);
  int* cur1   = (int*)alloc((size_t)NT * 4);
  int* el1    = (int*)alloc((size_t)NE * 4);
  int* deg2   = (int*)alloc((size_t)GS * 4);
  int* off2   = (int*)alloc((size_t)(GS + 1) * 4);
  int* cur2   = (int*)alloc((size_t)GS * 4);
  int* el2    = (int*)alloc((size_t)NE * 4);
  int* idxf   = (int*)alloc((size_t)GS * 4);
  float* qpos = (float*)alloc((size_t)GS * 3 * 4);
  int* mapv   = (int*)alloc((size_t)NT * 4);
  float* pooled = (float*)alloc((size_t)NG * 256 * 4);
  int* wctr   = (int*)alloc(128);

  hipMemsetAsync(deg1, 0, (size_t)NT * 4, stream);
  hipMemsetAsync(cur1, 0, (size_t)NT * 4, stream);
  hipMemsetAsync(deg2, 0, (size_t)GS * 4, stream);
  hipMemsetAsync(cur2, 0, (size_t)GS * 4, stream);
  hipMemsetAsync(mapv, 0xFF, (size_t)NT * 4, stream);  // -1
  hipMemsetAsync(pooled, 0, (size_t)NG * 256 * 4, stream);
  hipMemsetAsync(wctr, 0, 128, stream);

  // phase A (cooperative): fps ∥ {GCN layers 1-2}; workers exit early -> chip quiet for fps
  {
    void* ka[] = {(void*)&pos, (void*)&idxf, (void*)&qpos, (void*)&norm, (void*)&x,
                  (void*)&W1, (void*)&T1, (void*)&ei, (void*)&deg1,
                  (void*)&off1, (void*)&cur1, (void*)&el1,
                  (void*)&b1, (void*)&W2, (void*)&A, (void*)&b2, (void*)&Bf,
                  (void*)&wctr};
    hipLaunchCooperativeKernel((const void*)phaseA_kernel, dim3(8 + NWORK), dim3(256),
                               ka, 0, stream);
  }
  // fused radius + mapset + pointconv
  post1_kernel<<<64, 256, 0, stream>>>(pos, qpos, idxf, Bf, mapv, xint);
  // feat3 (4 samples/block) + deg2
  post2_kernel<<<NF3B + NE / 256, 256, 0, stream>>>(xint, idxf, norm, pos, x, W3, A,
                                                    ei, mapv, deg2);
  scan_kernel<<<1, 1024, 0, stream>>>(deg2, off2, GS);
  fill2_kernel<<<NE / 256, 256, 0, stream>>>(ei, mapv, off2, cur2, el2);
  // layer 3
  agg_kernel<<<GS, 256, 0, stream>>>(A, off2, el2, b3, Bf, 256);
  // pool + head
  pool_kernel<<<dim3(NG, NS / 256), 256, 0, stream>>>(Bf, pooled);
  head_kernel<<<1, 128, 0, stream>>>(pooled, lw, lb, outp);
}

// Round 12
// 2152.873 us; speedup vs baseline: 1.2661x; 1.1564x over previous
//
#include <hip/hip_runtime.h>
#include <hip/hip_bf16.h>

constexpr int NG   = 8;          // graphs
constexpr int NPG  = 4096;       // nodes per graph
constexpr int NT   = NG * NPG;   // 32768 total nodes
constexpr int NS   = 2048;       // fps samples per graph
constexpr int GS   = NG * NS;    // 16384
constexpr int KN   = 64;         // max neighbors
constexpr int NE   = NG * 65536; // 524288 edges
constexpr int NC   = 13;         // classes
constexpr int NWORK = 248;       // worker blocks in phaseA (blocks 8..255)
constexpr int NF3B = 4096;       // feat3 blocks in post2 (4 samples each)

__device__ __forceinline__ float inp_val(const float* norm, const float* pos, const float* x,
                                         int node, int dim) {
  if (dim < 3) return norm[(size_t)node * 3 + dim];
  if (dim < 6) return pos[(size_t)node * 3 + (dim - 3)];
  return x[(size_t)node * 2 + (dim - 6)];
}

// agent-scope arrive-and-wait barrier among the NWORK worker blocks
__device__ __forceinline__ void wbar(int* ctrs, int k, int target) {
  __syncthreads();
  __threadfence();
  if (threadIdx.x == 0) {
    __hip_atomic_fetch_add(&ctrs[k], 1, __ATOMIC_RELEASE, __HIP_MEMORY_SCOPE_AGENT);
    while (__hip_atomic_load(&ctrs[k], __ATOMIC_ACQUIRE, __HIP_MEMORY_SCOPE_AGENT) < target)
      __builtin_amdgcn_s_sleep(16);
  }
  __syncthreads();
}

// ---- phase A (cooperative, 256 blocks x 256 thr) ----
// blocks 0-7: fps (publishes done-flag wctr[9] at the end).
// blocks 8-255: feat1+deg1 -> scan -> fill1 -> agg1+feat2 -> agg2, then PURE-VALU spin
// until fps done (clock probe: zero memory traffic, keeps CUs non-idle).
// LDS padded to 84 KB -> exactly 1 block/CU, so spinners never share an fps CU.
__global__ __launch_bounds__(256, 1) void phaseA_kernel(
    const float* __restrict__ pos, int* __restrict__ idxf, float* __restrict__ qpos,
    const float* __restrict__ norm, const float* __restrict__ x,
    const float* __restrict__ W1, float* __restrict__ t1,
    const int* __restrict__ ei, int* __restrict__ deg,
    int* __restrict__ off1, int* __restrict__ cur1, int* __restrict__ el1,
    const float* __restrict__ b1, const float* __restrict__ W2, float* __restrict__ t2,
    const float* __restrict__ b2, float* __restrict__ h2,
    int* __restrict__ wctr) {
  __shared__ __align__(16) char smem[84000];
  if (blockIdx.x >= 8) {
    // ================= workers =================
    const int wb = blockIdx.x - 8;
    const int sub = threadIdx.x >> 6;   // 0..3 (one wave each)
    const int f = threadIdx.x & 63;
    float (*wrow)[80] = (float (*)[80])smem;
    int* sscan = (int*)(smem + 1280);
    // stage 0: feat1 (t1 = inp @ W1) + deg1
    for (int n0 = wb * 4; n0 < NT; n0 += NWORK * 4) {
      int n = n0 + sub;
      if (f < 8) wrow[sub][f] = inp_val(norm, pos, x, n, f);
      float acc = 0.f;  // same-wave LDS write->read, lockstep
#pragma unroll
      for (int i = 0; i < 8; ++i) acc += wrow[sub][i] * W1[i * 64 + f];
      t1[(size_t)n * 64 + f] = acc;
    }
    for (int e = wb * 256 + threadIdx.x; e < NE; e += NWORK * 256)
      atomicAdd(&deg[ei[NE + e]], 1);
    wbar(wctr, 0, NWORK);
    // stage 1: exclusive scan deg -> off1 (block 0 only)
    if (wb == 0) {
      int t = threadIdx.x, base = t * 128, s = 0;
      for (int i = 0; i < 128; ++i) s += deg[base + i];
      sscan[t] = s;
      __syncthreads();
      for (int d = 1; d < 256; d <<= 1) {
        int v = (t >= d) ? sscan[t - d] : 0;
        __syncthreads();
        sscan[t] += v;
        __syncthreads();
      }
      int excl = (t == 0) ? 0 : sscan[t - 1];
      for (int i = 0; i < 128; ++i) { off1[base + i] = excl; excl += deg[base + i]; }
      if (t == 255) off1[NT] = sscan[255];
    }
    wbar(wctr, 1, NWORK);
    // stage 2: fill1 (CSR edge lists)
    for (int e = wb * 256 + threadIdx.x; e < NE; e += NWORK * 256) {
      int sN = ei[e], dN = ei[NE + e];
      int p = off1[dN] + atomicAdd(&cur1[dN], 1);
      el1[p] = sN;
    }
    wbar(wctr, 2, NWORK);
    // stage 3: fused agg1 + feat2 (h1 stays in LDS)
    for (int n0 = wb * 4; n0 < NT; n0 += NWORK * 4) {
      int n = n0 + sub;
      int e0 = off1[n], e1 = off1[n + 1];
      float acc = 0.f;
      for (int j = e0; j < e1; ++j) acc += t1[(size_t)el1[j] * 64 + f];
      wrow[sub][f] = fmaxf(acc + b1[f], 0.f);
      if (f < 8) wrow[sub][64 + f] = inp_val(norm, pos, x, n, f);
      float a0 = 0.f, a1 = 0.f;
#pragma unroll 8
      for (int i = 0; i < 72; ++i) {
        float r = wrow[sub][i];
        a0 += r * W2[i * 128 + f];
        a1 += r * W2[i * 128 + 64 + f];
      }
      t2[(size_t)n * 128 + f] = a0;
      t2[(size_t)n * 128 + 64 + f] = a1;
    }
    wbar(wctr, 3, NWORK);
    // stage 4: agg2 (h2 = relu(sum t2 + b2))
    {
      const int f2 = threadIdx.x & 127, sub2 = threadIdx.x >> 7;
      for (int n0 = wb * 2; n0 < NT; n0 += NWORK * 2) {
        int n = n0 + sub2;
        int e0 = off1[n], e1 = off1[n + 1];
        float acc = 0.f;
        for (int j = e0; j < e1; ++j) acc += t2[(size_t)el1[j] * 128 + f2];
        h2[(size_t)n * 128 + f2] = fmaxf(acc + b2[f2], 0.f);
      }
    }
    // stage 5 (clock probe): pure-register FMA spin until fps done. No memory traffic
    // except one acquire-poll per ~4096-FMA burst. Keeps 248 CUs non-idle.
    {
      float r0 = 1.f + (float)threadIdx.x * 1e-6f;
      while (__hip_atomic_load(&wctr[9], __ATOMIC_ACQUIRE, __HIP_MEMORY_SCOPE_AGENT) < 8) {
        for (int it = 0; it < 4096; ++it) r0 = __fmaf_rn(r0, 1.0000001f, 1e-7f);
      }
      if (r0 == 123.456f) t1[0] = r0;  // unreachable; keeps the chain live
    }
    return;
  }
  // ================= FPS (round-7/9 arithmetic, bulk write at end) =================
  const int g = blockIdx.x;
  float4* qrec = (float4*)smem;                  // [NS] 32 KB
  int* irec = (int*)(smem + 32768);              // [NS] 8 KB
  float4 (*sq)[4] = (float4 (*)[4])(smem + 40960);
  int (*sidx)[4] = (int (*)[4])(smem + 41088);
  const float* pg = pos + (size_t)g * NPG * 3;
  const int tid = threadIdx.x;
  const int wave = tid >> 6, lane = tid & 63;
  const int p0 = tid * 16;

  float a[48];
  {
    const float4* pg4 = reinterpret_cast<const float4*>(pg + (size_t)p0 * 3);
#pragma unroll
    for (int j = 0; j < 12; ++j) {
      float4 t = pg4[j];
      a[4 * j + 0] = t.x; a[4 * j + 1] = t.y; a[4 * j + 2] = t.z; a[4 * j + 3] = t.w;
    }
  }
  float px[16], py[16], pz[16], mind[16];
#pragma unroll
  for (int i = 0; i < 16; ++i) {
    px[i] = a[3 * i]; py[i] = a[3 * i + 1]; pz[i] = a[3 * i + 2];
    mind[i] = __int_as_float(0x7f800000);  // +inf
  }
  float cx = pg[0], cy = pg[1], cz = pg[2];
  int idx_sel = 0;  // maintained by tid 0

  for (int s = 0; s < NS; ++s) {
    if (tid == 0) { irec[s] = idx_sel; qrec[s] = make_float4(cx, cy, cz, 0.f); }
    float bestv = -1.f, bx = 0.f, by = 0.f, bz = 0.f;
    int bi = 0;
#pragma unroll
    for (int i = 0; i < 16; ++i) {
      float dx = __fsub_rn(px[i], cx);
      float dy = __fsub_rn(py[i], cy);
      float dz = __fsub_rn(pz[i], cz);
      float dd = __fadd_rn(__fadd_rn(__fmul_rn(dx, dx), __fmul_rn(dy, dy)), __fmul_rn(dz, dz));
      float nm = fminf(mind[i], dd);
      mind[i] = nm;
      bool gt = nm > bestv;   // strict > keeps first occurrence
      bestv = gt ? nm : bestv;
      bx = gt ? px[i] : bx;
      by = gt ? py[i] : by;
      bz = gt ? pz[i] : bz;
      bi = gt ? i : bi;
    }
    float v = bestv;
    v = fmaxf(v, __int_as_float(__builtin_amdgcn_update_dpp(0, __float_as_int(v), 0x111, 0xF, 0xF, true)));
    v = fmaxf(v, __int_as_float(__builtin_amdgcn_update_dpp(0, __float_as_int(v), 0x112, 0xF, 0xF, true)));
    v = fmaxf(v, __int_as_float(__builtin_amdgcn_update_dpp(0, __float_as_int(v), 0x114, 0xF, 0xF, true)));
    v = fmaxf(v, __int_as_float(__builtin_amdgcn_update_dpp(0, __float_as_int(v), 0x118, 0xF, 0xF, true)));
    v = fmaxf(v, __int_as_float(__builtin_amdgcn_update_dpp(0, __float_as_int(v), 0x142, 0xF, 0xF, true)));
    v = fmaxf(v, __int_as_float(__builtin_amdgcn_update_dpp(0, __float_as_int(v), 0x143, 0xF, 0xF, true)));
    int maxbits = __builtin_amdgcn_readlane(__float_as_int(v), 63);
    float wavemax = __int_as_float(maxbits);
    unsigned long long ball = __ballot(bestv == wavemax);
    int winner = __ffsll(ball) - 1;  // lowest lane = lowest index (contiguous ownership)
    int b = s & 1;
    if (lane == winner) {
      sq[b][wave] = make_float4(bx, by, bz, wavemax);
      sidx[b][wave] = p0 + bi;
    }
    __syncthreads();
    float4 q0 = sq[b][0], q1 = sq[b][1], q2 = sq[b][2], q3 = sq[b][3];
    float4 qs = q3;
    if (q2.w >= qs.w) qs = q2;   // >= toward lower wave = lowest index on ties
    if (q1.w >= qs.w) qs = q1;
    if (q0.w >= qs.w) qs = q0;
    cx = qs.x; cy = qs.y; cz = qs.z;
    if (tid == 0) {  // resolve record index off the critical path
      int i0 = sidx[b][0], i1 = sidx[b][1], i2 = sidx[b][2], i3 = sidx[b][3];
      float r = q3.w; int is = i3;
      if (q2.w >= r) { r = q2.w; is = i2; }
      if (q1.w >= r) { r = q1.w; is = i1; }
      if (q0.w >= r) { r = q0.w; is = i0; }
      idx_sel = is;
    }
  }
  __syncthreads();
  for (int j = tid; j < NS; j += 256) {
    idxf[g * NS + j] = g * NPG + irec[j];
    float4 q = qrec[j];
    size_t m = (size_t)(g * NS + j) * 3;
    qpos[m + 0] = q.x; qpos[m + 1] = q.y; qpos[m + 2] = q.z;
  }
  __threadfence();
  __syncthreads();
  if (tid == 0)
    __hip_atomic_fetch_add(&wctr[9], 1, __ATOMIC_RELEASE, __HIP_MEMORY_SCOPE_AGENT);
}

// ---------------- radius neighbors (first K lowest-index within R) + mapset ----------------
__global__ __launch_bounds__(256) void radius_kernel(const float* __restrict__ pos,
                                                     const float* __restrict__ qpos,
                                                     int* __restrict__ cols,
                                                     int* __restrict__ cnt,
                                                     const int* __restrict__ idxf,
                                                     int* __restrict__ mp) {
  const int g = blockIdx.x;
  __shared__ float sx[NPG], sy[NPG], sz[NPG];
  const float* pg = pos + (size_t)g * NPG * 3;
  for (int i = threadIdx.x; i < NPG * 3; i += 256) {
    float v = pg[i]; int node = i / 3, c = i - node * 3;
    if (c == 0) sx[node] = v; else if (c == 1) sy[node] = v; else sz[node] = v;
  }
  __syncthreads();
  int m = g * NS + blockIdx.y * 256 + threadIdx.x;
  mp[idxf[m]] = m;  // fused mapset (threads <-> samples 1:1 over the grid)
  float qx = qpos[(size_t)m * 3], qy = qpos[(size_t)m * 3 + 1], qz = qpos[(size_t)m * 3 + 2];
  int* out = cols + (size_t)m * KN;
  int c = 0;
  for (int i = 0; i < NPG; ++i) {
    float dx = __fsub_rn(sx[i], qx);
    float dy = __fsub_rn(sy[i], qy);
    float dz = __fsub_rn(sz[i], qz);
    float d2 = __fadd_rn(__fadd_rn(__fmul_rn(dx, dx), __fmul_rn(dy, dy)), __fmul_rn(dz, dz));
    if (d2 < 0.16f) {
      out[c++] = i;
      if (c == KN) break;
    }
  }
  cnt[m] = c;
}

// ---------------- PointConv: max over neighbors of [h2[c], p[c]-q] ----------------
__global__ __launch_bounds__(64) void pointconv_kernel(const float* __restrict__ h2,
                                                       const float* __restrict__ pos,
                                                       const float* __restrict__ qpos,
                                                       const int* __restrict__ cols,
                                                       const int* __restrict__ cnt,
                                                       float* __restrict__ xint) {
  int m = blockIdx.x, t = threadIdx.x;
  int g = m / NS;
  int n = cnt[m];
  const int* cl = cols + (size_t)m * KN;
  float m0 = -INFINITY, m1 = -INFINITY, mp = -INFINITY;
  for (int k = 0; k < n; ++k) {
    int c = cl[k];
    size_t base = (size_t)(g * NPG + c);
    m0 = fmaxf(m0, h2[base * 128 + t]);
    m1 = fmaxf(m1, h2[base * 128 + 64 + t]);
    if (t < 3) mp = fmaxf(mp, pos[base * 3 + t]);
  }
  float* xo = xint + (size_t)m * 131;
  xo[t] = m0;
  xo[64 + t] = m1;
  if (t < 3) xo[128 + t] = __fsub_rn(mp, qpos[(size_t)m * 3 + t]);
}

// ---- post2: feat3 (4 samples/block, blocks 0..NF3B-1) + deg2 (blocks NF3B..) ----
__global__ void post2_kernel(const float* __restrict__ xint, const int* __restrict__ idxf,
                             const float* __restrict__ norm, const float* __restrict__ pos,
                             const float* __restrict__ x, const float* __restrict__ W3,
                             float* __restrict__ t3,
                             const int* __restrict__ ei, const int* __restrict__ mp,
                             int* __restrict__ deg) {
  if (blockIdx.x >= NF3B) {
    int e = (blockIdx.x - NF3B) * 256 + threadIdx.x;  // exactly NE threads
    int ns = mp[ei[e]], nd = mp[ei[NE + e]];
    if (ns >= 0 && nd >= 0) atomicAdd(&deg[nd], 1);
    return;
  }
  __shared__ float srow[4][140];
  const int m0 = blockIdx.x * 4;
  for (int j = threadIdx.x; j < 4 * 139; j += 256) {
    int sub = j / 139, i = j - sub * 139;
    int m = m0 + sub;
    srow[sub][i] = (i < 131) ? xint[(size_t)m * 131 + i]
                             : inp_val(norm, pos, x, idxf[m], i - 131);
  }
  __syncthreads();
  int f = threadIdx.x;
  float a0 = 0.f, a1 = 0.f, a2 = 0.f, a3 = 0.f;
#pragma unroll 8
  for (int i = 0; i < 139; ++i) {
    float wv = W3[i * 256 + f];
    a0 += srow[0][i] * wv;
    a1 += srow[1][i] * wv;
    a2 += srow[2][i] * wv;
    a3 += srow[3][i] * wv;
  }
  t3[(size_t)(m0 + 0) * 256 + f] = a0;
  t3[(size_t)(m0 + 1) * 256 + f] = a1;
  t3[(size_t)(m0 + 2) * 256 + f] = a2;
  t3[(size_t)(m0 + 3) * 256 + f] = a3;
}

__global__ void fill2_kernel(const int* __restrict__ ei, const int* __restrict__ mp,
                             const int* __restrict__ off, int* __restrict__ cur,
                             int* __restrict__ el) {
  int e = blockIdx.x * 256 + threadIdx.x;
  if (e < NE) {
    int ns = mp[ei[e]], nd = mp[ei[NE + e]];
    if (ns >= 0 && nd >= 0) {
      int p = off[nd] + atomicAdd(&cur[nd], 1);
      el[p] = ns;
    }
  }
}

// single-block exclusive scan, n <= 32768, writes out[0..n]
__global__ __launch_bounds__(1024) void scan_kernel(const int* __restrict__ in,
                                                    int* __restrict__ out, int n) {
  __shared__ int ls[1024];
  int tid = threadIdx.x;
  int per = (n + 1023) >> 10;
  int base = tid * per;
  int s = 0;
  for (int i = 0; i < per; ++i) { int idx = base + i; if (idx < n) s += in[idx]; }
  ls[tid] = s;
  __syncthreads();
  for (int d = 1; d < 1024; d <<= 1) {
    int v = (tid >= d) ? ls[tid - d] : 0;
    __syncthreads();
    ls[tid] += v;
    __syncthreads();
  }
  int excl = (tid == 0) ? 0 : ls[tid - 1];
  for (int i = 0; i < per; ++i) {
    int idx = base + i;
    if (idx < n) { out[idx] = excl; excl += in[idx]; }
  }
  if (tid == 1023) out[n] = ls[1023];
}

// gather-side GCN aggregation: out[node,f] = relu(b[f] + sum_{src in list} t[src,f])
__global__ void agg_kernel(const float* __restrict__ t, const int* __restrict__ off,
                           const int* __restrict__ el, const float* __restrict__ b,
                           float* __restrict__ out, int F) {
  int node = blockIdx.x, f = threadIdx.x;
  int e0 = off[node], e1 = off[node + 1];
  float acc = 0.f;
  for (int j = e0; j < e1; ++j) acc += t[(size_t)el[j] * F + f];
  out[(size_t)node * F + f] = fmaxf(acc + b[f], 0.f);
}

// ---------------- pooling + head ----------------
__global__ void pool_kernel(const float* __restrict__ h3, float* __restrict__ pooled) {
  int g = blockIdx.x, ch = blockIdx.y, f = threadIdx.x;  // 256 threads
  float mx = 0.f;  // h3 >= 0 (relu)
  size_t base = ((size_t)g * NS + (size_t)ch * 256) * 256 + f;
  for (int s = 0; s < 256; ++s) mx = fmaxf(mx, h3[base + (size_t)s * 256]);
  atomicMax((int*)pooled + g * 256 + f, __float_as_int(mx));
}

__global__ void head_kernel(const float* __restrict__ pooled, const float* __restrict__ lw,
                            const float* __restrict__ lb, float* __restrict__ outp) {
  __shared__ float lg[NG * NC];
  int t = threadIdx.x;  // 128 threads
  if (t < NG * NC) {
    int g = t / NC, c = t % NC;
    float acc = lb[c];
    for (int k = 0; k < 256; ++k) acc += pooled[g * 256 + k] * lw[k * NC + c];
    lg[t] = acc;
  }
  __syncthreads();
  if (t < NG) {
    int g = t;
    float mx = -INFINITY;
    for (int c = 0; c < NC; ++c) mx = fmaxf(mx, lg[g * NC + c]);
    float sum = 0.f;
    for (int c = 0; c < NC; ++c) sum += expf(lg[g * NC + c] - mx);
    float lse = logf(sum);
    float ov[NC];
    float mx2 = -INFINITY;
    for (int c = 0; c < NC; ++c) {
      ov[c] = lg[g * NC + c] - mx - lse;
      outp[g * NC + c] = ov[c];
      mx2 = fmaxf(mx2, ov[c]);
    }
    float s2 = 0.f;
    for (int c = 0; c < NC; ++c) s2 += expf(ov[c] - mx2);
    for (int c = 0; c < NC; ++c) outp[NG * NC + g * NC + c] = expf(ov[c] - mx2) / s2;
  }
}

extern "C" void kernel_launch(void* const* d_in, const int* in_sizes, int n_in,
                              void* d_out, int out_size, void* d_ws, size_t ws_size,
                              hipStream_t stream) {
  const float* norm = (const float*)d_in[0];
  const float* pos  = (const float*)d_in[1];
  const float* x    = (const float*)d_in[2];
  const int* ei     = (const int*)d_in[3];   // int32! row0 = src, row1 = dst
  // d_in[4] = batch (int32, unused)
  const float* W1 = (const float*)d_in[5];
  const float* b1 = (const float*)d_in[6];
  const float* W2 = (const float*)d_in[7];
  const float* b2 = (const float*)d_in[8];
  const float* W3 = (const float*)d_in[9];
  const float* b3 = (const float*)d_in[10];
  const float* lw = (const float*)d_in[11];
  const float* lb = (const float*)d_in[12];
  float* outp = (float*)d_out;

  char* w = (char*)d_ws;
  size_t o = 0;
  auto alloc = [&](size_t bytes) -> void* {
    void* p = w + o;
    o = (o + bytes + 255) & ~(size_t)255;
    return p;
  };
  float* A    = (float*)alloc((size_t)NT * 128 * 4);  // t2 -> t3
  float* Bf   = (float*)alloc((size_t)NT * 128 * 4);  // h2 -> h3
  float* T1   = (float*)alloc((size_t)NT * 64 * 4);   // t1
  float* xint = (float*)alloc((size_t)GS * 131 * 4);
  int* cols   = (int*)alloc((size_t)GS * KN * 4);
  int* cnt    = (int*)alloc((size_t)GS * 4);
  int* deg1   = (int*)alloc((size_t)NT * 4);
  int* off1   = (int*)alloc((size_t)(NT + 1) * 4);
  int* cur1   = (int*)alloc((size_t)NT * 4);
  int* el1    = (int*)alloc((size_t)NE * 4);
  int* deg2   = (int*)alloc((size_t)GS * 4);
  int* off2   = (int*)alloc((size_t)(GS + 1) * 4);
  int* cur2   = (int*)alloc((size_t)GS * 4);
  int* el2    = (int*)alloc((size_t)NE * 4);
  int* idxf   = (int*)alloc((size_t)GS * 4);
  float* qpos = (float*)alloc((size_t)GS * 3 * 4);
  int* mapv   = (int*)alloc((size_t)NT * 4);
  float* pooled = (float*)alloc((size_t)NG * 256 * 4);
  int* wctr   = (int*)alloc(128);

  hipMemsetAsync(deg1, 0, (size_t)NT * 4, stream);
  hipMemsetAsync(cur1, 0, (size_t)NT * 4, stream);
  hipMemsetAsync(deg2, 0, (size_t)GS * 4, stream);
  hipMemsetAsync(cur2, 0, (size_t)GS * 4, stream);
  hipMemsetAsync(mapv, 0xFF, (size_t)NT * 4, stream);  // -1
  hipMemsetAsync(pooled, 0, (size_t)NG * 256 * 4, stream);
  hipMemsetAsync(wctr, 0, 128, stream);

  // phase A (cooperative): fps ∥ {GCN layers 1-2, then pure-VALU spin (clock probe)}
  {
    void* ka[] = {(void*)&pos, (void*)&idxf, (void*)&qpos, (void*)&norm, (void*)&x,
                  (void*)&W1, (void*)&T1, (void*)&ei, (void*)&deg1,
                  (void*)&off1, (void*)&cur1, (void*)&el1,
                  (void*)&b1, (void*)&W2, (void*)&A, (void*)&b2, (void*)&Bf,
                  (void*)&wctr};
    hipLaunchCooperativeKernel((const void*)phaseA_kernel, dim3(8 + NWORK), dim3(256),
                               ka, 0, stream);
  }
  // neighborhoods (radius + fused mapset), then pointconv with full TLP
  radius_kernel<<<dim3(NG, NS / 256), 256, 0, stream>>>(pos, qpos, cols, cnt, idxf, mapv);
  pointconv_kernel<<<GS, 64, 0, stream>>>(Bf, pos, qpos, cols, cnt, xint);
  // feat3 (4 samples/block) + deg2
  post2_kernel<<<NF3B + NE / 256, 256, 0, stream>>>(xint, idxf, norm, pos, x, W3, A,
                                                    ei, mapv, deg2);
  scan_kernel<<<1, 1024, 0, stream>>>(deg2, off2, GS);
  fill2_kernel<<<NE / 256, 256, 0, stream>>>(ei, mapv, off2, cur2, el2);
  // layer 3
  agg_kernel<<<GS, 256, 0, stream>>>(A, off2, el2, b3, Bf, 256);
  // pool + head
  pool_kernel<<<dim3(NG, NS / 256), 256, 0, stream>>>(Bf, pooled);
  head_kernel<<<1, 128, 0, stream>>>(pooled, lw, lb, outp);
}

// Round 13
// 2069.142 us; speedup vs baseline: 1.3173x; 1.0405x over previous
//
#include <hip/hip_runtime.h>
#include <hip/hip_bf16.h>

constexpr int NG   = 8;          // graphs
constexpr int NPG  = 4096;       // nodes per graph
constexpr int NT   = NG * NPG;   // 32768 total nodes
constexpr int NS   = 2048;       // fps samples per graph
constexpr int GS   = NG * NS;    // 16384
constexpr int KN   = 64;         // max neighbors
constexpr int NE   = NG * 65536; // 524288 edges
constexpr int NC   = 13;         // classes
constexpr int NWORK = 248;       // worker blocks in phaseA (blocks 8..255)
constexpr int SPB  = 16;         // samples per block in post2 feat3
constexpr int NF3B = GS / SPB;   // 1024 feat3 blocks

__device__ __forceinline__ float inp_val(const float* norm, const float* pos, const float* x,
                                         int node, int dim) {
  if (dim < 3) return norm[(size_t)node * 3 + dim];
  if (dim < 6) return pos[(size_t)node * 3 + (dim - 3)];
  return x[(size_t)node * 2 + (dim - 6)];
}

// agent-scope arrive-and-wait barrier among the NWORK worker blocks
__device__ __forceinline__ void wbar(int* ctrs, int k, int target) {
  __syncthreads();
  __threadfence();
  if (threadIdx.x == 0) {
    __hip_atomic_fetch_add(&ctrs[k], 1, __ATOMIC_RELEASE, __HIP_MEMORY_SCOPE_AGENT);
    while (__hip_atomic_load(&ctrs[k], __ATOMIC_ACQUIRE, __HIP_MEMORY_SCOPE_AGENT) < target)
      __builtin_amdgcn_s_sleep(16);
  }
  __syncthreads();
}

// ---- phase A (cooperative, 256 blocks x 256 thr) — r9/r11 measured-good form ----
// blocks 0-7: fps. blocks 8-255: feat1+deg1 -> scan -> fill1 -> agg1+feat2 -> agg2, exit.
__global__ __launch_bounds__(256, 1) void phaseA_kernel(
    const float* __restrict__ pos, int* __restrict__ idxf, float* __restrict__ qpos,
    const float* __restrict__ norm, const float* __restrict__ x,
    const float* __restrict__ W1, float* __restrict__ t1,
    const int* __restrict__ ei, int* __restrict__ deg,
    int* __restrict__ off1, int* __restrict__ cur1, int* __restrict__ el1,
    const float* __restrict__ b1, const float* __restrict__ W2, float* __restrict__ t2,
    const float* __restrict__ b2, float* __restrict__ h2,
    int* __restrict__ wctr) {
  if (blockIdx.x >= 8) {
    // ================= workers =================
    const int wb = blockIdx.x - 8;
    const int sub = threadIdx.x >> 6;   // 0..3 (one wave each)
    const int f = threadIdx.x & 63;
    __shared__ float wrow[4][80];
    __shared__ int sscan[256];
    // stage 0: feat1 (t1 = inp @ W1) + deg1
    for (int n0 = wb * 4; n0 < NT; n0 += NWORK * 4) {
      int n = n0 + sub;
      if (f < 8) wrow[sub][f] = inp_val(norm, pos, x, n, f);
      float acc = 0.f;  // same-wave LDS write->read, lockstep
#pragma unroll
      for (int i = 0; i < 8; ++i) acc += wrow[sub][i] * W1[i * 64 + f];
      t1[(size_t)n * 64 + f] = acc;
    }
    for (int e = wb * 256 + threadIdx.x; e < NE; e += NWORK * 256)
      atomicAdd(&deg[ei[NE + e]], 1);
    wbar(wctr, 0, NWORK);
    // stage 1: exclusive scan deg -> off1 (block 0 only)
    if (wb == 0) {
      int t = threadIdx.x, base = t * 128, s = 0;
      for (int i = 0; i < 128; ++i) s += deg[base + i];
      sscan[t] = s;
      __syncthreads();
      for (int d = 1; d < 256; d <<= 1) {
        int v = (t >= d) ? sscan[t - d] : 0;
        __syncthreads();
        sscan[t] += v;
        __syncthreads();
      }
      int excl = (t == 0) ? 0 : sscan[t - 1];
      for (int i = 0; i < 128; ++i) { off1[base + i] = excl; excl += deg[base + i]; }
      if (t == 255) off1[NT] = sscan[255];
    }
    wbar(wctr, 1, NWORK);
    // stage 2: fill1 (CSR edge lists)
    for (int e = wb * 256 + threadIdx.x; e < NE; e += NWORK * 256) {
      int sN = ei[e], dN = ei[NE + e];
      int p = off1[dN] + atomicAdd(&cur1[dN], 1);
      el1[p] = sN;
    }
    wbar(wctr, 2, NWORK);
    // stage 3: fused agg1 + feat2 (h1 stays in LDS)
    for (int n0 = wb * 4; n0 < NT; n0 += NWORK * 4) {
      int n = n0 + sub;
      int e0 = off1[n], e1 = off1[n + 1];
      float acc = 0.f;
      for (int j = e0; j < e1; ++j) acc += t1[(size_t)el1[j] * 64 + f];
      wrow[sub][f] = fmaxf(acc + b1[f], 0.f);
      if (f < 8) wrow[sub][64 + f] = inp_val(norm, pos, x, n, f);
      float a0 = 0.f, a1 = 0.f;
#pragma unroll 8
      for (int i = 0; i < 72; ++i) {
        float r = wrow[sub][i];
        a0 += r * W2[i * 128 + f];
        a1 += r * W2[i * 128 + 64 + f];
      }
      t2[(size_t)n * 128 + f] = a0;
      t2[(size_t)n * 128 + 64 + f] = a1;
    }
    wbar(wctr, 3, NWORK);
    // stage 4: agg2 (h2 = relu(sum t2 + b2)); then exit -> chip quiet for fps
    {
      const int f2 = threadIdx.x & 127, sub2 = threadIdx.x >> 7;
      for (int n0 = wb * 2; n0 < NT; n0 += NWORK * 2) {
        int n = n0 + sub2;
        int e0 = off1[n], e1 = off1[n + 1];
        float acc = 0.f;
        for (int j = e0; j < e1; ++j) acc += t2[(size_t)el1[j] * 128 + f2];
        h2[(size_t)n * 128 + f2] = fmaxf(acc + b2[f2], 0.f);
      }
    }
    return;
  }
  // ================= FPS (round-7/9 arithmetic, bulk write at end) =================
  const int g = blockIdx.x;
  __shared__ float4 sq[2][4];
  __shared__ int sidx[2][4];
  __shared__ float4 qrec[NS];  // 32 KB
  __shared__ int irec[NS];     // 8 KB
  const float* pg = pos + (size_t)g * NPG * 3;
  const int tid = threadIdx.x;
  const int wave = tid >> 6, lane = tid & 63;
  const int p0 = tid * 16;

  float a[48];
  {
    const float4* pg4 = reinterpret_cast<const float4*>(pg + (size_t)p0 * 3);
#pragma unroll
    for (int j = 0; j < 12; ++j) {
      float4 t = pg4[j];
      a[4 * j + 0] = t.x; a[4 * j + 1] = t.y; a[4 * j + 2] = t.z; a[4 * j + 3] = t.w;
    }
  }
  float px[16], py[16], pz[16], mind[16];
#pragma unroll
  for (int i = 0; i < 16; ++i) {
    px[i] = a[3 * i]; py[i] = a[3 * i + 1]; pz[i] = a[3 * i + 2];
    mind[i] = __int_as_float(0x7f800000);  // +inf
  }
  float cx = pg[0], cy = pg[1], cz = pg[2];
  int idx_sel = 0;  // maintained by tid 0

  for (int s = 0; s < NS; ++s) {
    if (tid == 0) { irec[s] = idx_sel; qrec[s] = make_float4(cx, cy, cz, 0.f); }
    float bestv = -1.f, bx = 0.f, by = 0.f, bz = 0.f;
    int bi = 0;
#pragma unroll
    for (int i = 0; i < 16; ++i) {
      float dx = __fsub_rn(px[i], cx);
      float dy = __fsub_rn(py[i], cy);
      float dz = __fsub_rn(pz[i], cz);
      float dd = __fadd_rn(__fadd_rn(__fmul_rn(dx, dx), __fmul_rn(dy, dy)), __fmul_rn(dz, dz));
      float nm = fminf(mind[i], dd);
      mind[i] = nm;
      bool gt = nm > bestv;   // strict > keeps first occurrence
      bestv = gt ? nm : bestv;
      bx = gt ? px[i] : bx;
      by = gt ? py[i] : by;
      bz = gt ? pz[i] : bz;
      bi = gt ? i : bi;
    }
    float v = bestv;
    v = fmaxf(v, __int_as_float(__builtin_amdgcn_update_dpp(0, __float_as_int(v), 0x111, 0xF, 0xF, true)));
    v = fmaxf(v, __int_as_float(__builtin_amdgcn_update_dpp(0, __float_as_int(v), 0x112, 0xF, 0xF, true)));
    v = fmaxf(v, __int_as_float(__builtin_amdgcn_update_dpp(0, __float_as_int(v), 0x114, 0xF, 0xF, true)));
    v = fmaxf(v, __int_as_float(__builtin_amdgcn_update_dpp(0, __float_as_int(v), 0x118, 0xF, 0xF, true)));
    v = fmaxf(v, __int_as_float(__builtin_amdgcn_update_dpp(0, __float_as_int(v), 0x142, 0xF, 0xF, true)));
    v = fmaxf(v, __int_as_float(__builtin_amdgcn_update_dpp(0, __float_as_int(v), 0x143, 0xF, 0xF, true)));
    int maxbits = __builtin_amdgcn_readlane(__float_as_int(v), 63);
    float wavemax = __int_as_float(maxbits);
    unsigned long long ball = __ballot(bestv == wavemax);
    int winner = __ffsll(ball) - 1;  // lowest lane = lowest index (contiguous ownership)
    int b = s & 1;
    if (lane == winner) {
      sq[b][wave] = make_float4(bx, by, bz, wavemax);
      sidx[b][wave] = p0 + bi;
    }
    __syncthreads();
    float4 q0 = sq[b][0], q1 = sq[b][1], q2 = sq[b][2], q3 = sq[b][3];
    float4 qs = q3;
    if (q2.w >= qs.w) qs = q2;   // >= toward lower wave = lowest index on ties
    if (q1.w >= qs.w) qs = q1;
    if (q0.w >= qs.w) qs = q0;
    cx = qs.x; cy = qs.y; cz = qs.z;
    if (tid == 0) {  // resolve record index off the critical path
      int i0 = sidx[b][0], i1 = sidx[b][1], i2 = sidx[b][2], i3 = sidx[b][3];
      float r = q3.w; int is = i3;
      if (q2.w >= r) { r = q2.w; is = i2; }
      if (q1.w >= r) { r = q1.w; is = i1; }
      if (q0.w >= r) { r = q0.w; is = i0; }
      idx_sel = is;
    }
  }
  __syncthreads();
  for (int j = tid; j < NS; j += 256) {
    idxf[g * NS + j] = g * NPG + irec[j];
    float4 q = qrec[j];
    size_t m = (size_t)(g * NS + j) * 3;
    qpos[m + 0] = q.x; qpos[m + 1] = q.y; qpos[m + 2] = q.z;
  }
}

// ---- radius: 4 lanes/sample stripe scan, exact first-K-lowest-index; + mapset ----
// 256 blocks x 256 thr; block = 64 samples of one graph; lane j scans stripe [j*1024,(j+1)*1024)
__global__ __launch_bounds__(256, 1) void radius_kernel(
    const float* __restrict__ pos, const float* __restrict__ qpos,
    int* __restrict__ cols, int* __restrict__ cnt,
    const int* __restrict__ idxf, int* __restrict__ mp) {
  __shared__ float spx[NPG], spy[NPG], spz[NPG];   // 48 KB
  __shared__ int sbuf[KN][64][4];                  // 64 KB, [c][group][j]: 2-lane/bank writes
  const int g = blockIdx.x >> 5;
  const int s0 = (blockIdx.x & 31) * 64;
  const float* pgc = pos + (size_t)g * NPG * 3;
  for (int i = threadIdx.x; i < NPG * 3; i += 256) {
    float v = pgc[i]; int node = i / 3, cc = i - node * 3;
    if (cc == 0) spx[node] = v; else if (cc == 1) spy[node] = v; else spz[node] = v;
  }
  __syncthreads();
  const int group = threadIdx.x >> 2;   // 0..63 -> sample
  const int j = threadIdx.x & 3;        // stripe
  const int m = g * NS + s0 + group;
  if (j == 0) mp[idxf[m]] = m;          // fused mapset
  const float qx = qpos[(size_t)m * 3], qy = qpos[(size_t)m * 3 + 1],
              qz = qpos[(size_t)m * 3 + 2];
  int c = 0;
  const int i0 = j * 1024;
  for (int i = i0; i < i0 + 1024; ++i) {
    float dx = __fsub_rn(spx[i], qx);
    float dy = __fsub_rn(spy[i], qy);
    float dz = __fsub_rn(spz[i], qz);
    float d2 = __fadd_rn(__fadd_rn(__fmul_rn(dx, dx), __fmul_rn(dy, dy)), __fmul_rn(dz, dz));
    if (d2 < 0.16f) {
      sbuf[c][group][j] = i;
      if (++c == KN) break;   // a stripe can contribute at most KN
    }
  }
  // 4-lane prefix over stripe counts (lowest stripe = lowest indices first)
  const int lbase = (threadIdx.x & 63) & ~3;
  int c0 = __shfl(c, lbase + 0), c1 = __shfl(c, lbase + 1),
      c2 = __shfl(c, lbase + 2), c3 = __shfl(c, lbase + 3);
  int pre = (j > 0 ? c0 : 0) + (j > 1 ? c1 : 0) + (j > 2 ? c2 : 0);
  int total = c0 + c1 + c2 + c3;
  if (j == 0) cnt[m] = total < KN ? total : KN;
  int take = KN - pre;
  take = take < 0 ? 0 : (take > c ? c : take);
  int* outp = cols + (size_t)m * KN + pre;
  for (int i = 0; i < take; ++i) outp[i] = sbuf[i][group][j];
}

// ---------------- PointConv: max over neighbors of [h2[c], p[c]-q] ----------------
__global__ __launch_bounds__(64) void pointconv_kernel(const float* __restrict__ h2,
                                                       const float* __restrict__ pos,
                                                       const float* __restrict__ qpos,
                                                       const int* __restrict__ cols,
                                                       const int* __restrict__ cnt,
                                                       float* __restrict__ xint) {
  int m = blockIdx.x, t = threadIdx.x;
  int g = m / NS;
  int n = cnt[m];
  const int* cl = cols + (size_t)m * KN;
  float m0 = -INFINITY, m1 = -INFINITY, mp = -INFINITY;
  for (int k = 0; k < n; ++k) {
    int c = cl[k];
    size_t base = (size_t)(g * NPG + c);
    m0 = fmaxf(m0, h2[base * 128 + t]);
    m1 = fmaxf(m1, h2[base * 128 + 64 + t]);
    if (t < 3) mp = fmaxf(mp, pos[base * 3 + t]);
  }
  float* xo = xint + (size_t)m * 131;
  xo[t] = m0;
  xo[64 + t] = m1;
  if (t < 3) xo[128 + t] = __fsub_rn(mp, qpos[(size_t)m * 3 + t]);
}

// ---- post2: feat3 (SPB samples/block, blocks 0..NF3B-1) + deg2 (blocks NF3B..) ----
__global__ void post2_kernel(const float* __restrict__ xint, const int* __restrict__ idxf,
                             const float* __restrict__ norm, const float* __restrict__ pos,
                             const float* __restrict__ x, const float* __restrict__ W3,
                             float* __restrict__ t3,
                             const int* __restrict__ ei, const int* __restrict__ mp,
                             int* __restrict__ deg) {
  if (blockIdx.x >= NF3B) {
    int e = (blockIdx.x - NF3B) * 256 + threadIdx.x;  // exactly NE threads
    int ns = mp[ei[e]], nd = mp[ei[NE + e]];
    if (ns >= 0 && nd >= 0) atomicAdd(&deg[nd], 1);
    return;
  }
  __shared__ float srow[SPB][140];
  const int m0 = blockIdx.x * SPB;
  for (int jj = threadIdx.x; jj < SPB * 139; jj += 256) {
    int sub = jj / 139, i = jj - sub * 139;
    int m = m0 + sub;
    srow[sub][i] = (i < 131) ? xint[(size_t)m * 131 + i]
                             : inp_val(norm, pos, x, idxf[m], i - 131);
  }
  __syncthreads();
  int f = threadIdx.x;
  float acc[SPB];
#pragma unroll
  for (int s = 0; s < SPB; ++s) acc[s] = 0.f;
#pragma unroll 4
  for (int i = 0; i < 139; ++i) {
    float wv = W3[i * 256 + f];
#pragma unroll
    for (int s = 0; s < SPB; ++s) acc[s] += srow[s][i] * wv;
  }
#pragma unroll
  for (int s = 0; s < SPB; ++s) t3[(size_t)(m0 + s) * 256 + f] = acc[s];
}

__global__ void fill2_kernel(const int* __restrict__ ei, const int* __restrict__ mp,
                             const int* __restrict__ off, int* __restrict__ cur,
                             int* __restrict__ el) {
  int e = blockIdx.x * 256 + threadIdx.x;
  if (e < NE) {
    int ns = mp[ei[e]], nd = mp[ei[NE + e]];
    if (ns >= 0 && nd >= 0) {
      int p = off[nd] + atomicAdd(&cur[nd], 1);
      el[p] = ns;
    }
  }
}

// single-block exclusive scan, n <= 32768, writes out[0..n]
__global__ __launch_bounds__(1024) void scan_kernel(const int* __restrict__ in,
                                                    int* __restrict__ out, int n) {
  __shared__ int ls[1024];
  int tid = threadIdx.x;
  int per = (n + 1023) >> 10;
  int base = tid * per;
  int s = 0;
  for (int i = 0; i < per; ++i) { int idx = base + i; if (idx < n) s += in[idx]; }
  ls[tid] = s;
  __syncthreads();
  for (int d = 1; d < 1024; d <<= 1) {
    int v = (tid >= d) ? ls[tid - d] : 0;
    __syncthreads();
    ls[tid] += v;
    __syncthreads();
  }
  int excl = (tid == 0) ? 0 : ls[tid - 1];
  for (int i = 0; i < per; ++i) {
    int idx = base + i;
    if (idx < n) { out[idx] = excl; excl += in[idx]; }
  }
  if (tid == 1023) out[n] = ls[1023];
}

// ---- agg3 + pool fused: h3 never materialized; relu'd value atomicMax'd into pooled ----
__global__ void aggpool_kernel(const float* __restrict__ t, const int* __restrict__ off,
                               const int* __restrict__ el, const float* __restrict__ b,
                               float* __restrict__ pooled) {
  int node = blockIdx.x, f = threadIdx.x;  // 256 threads
  int e0 = off[node], e1 = off[node + 1];
  float acc = 0.f;
  for (int j = e0; j < e1; ++j) acc += t[(size_t)el[j] * 256 + f];
  float val = fmaxf(acc + b[f], 0.f);  // >= 0, so int-compare atomicMax is exact
  atomicMax((int*)pooled + (node >> 11) * 256 + f, __float_as_int(val));
}

__global__ void head_kernel(const float* __restrict__ pooled, const float* __restrict__ lw,
                            const float* __restrict__ lb, float* __restrict__ outp) {
  __shared__ float lg[NG * NC];
  int t = threadIdx.x;  // 128 threads
  if (t < NG * NC) {
    int g = t / NC, c = t % NC;
    float acc = lb[c];
    for (int k = 0; k < 256; ++k) acc += pooled[g * 256 + k] * lw[k * NC + c];
    lg[t] = acc;
  }
  __syncthreads();
  if (t < NG) {
    int g = t;
    float mx = -INFINITY;
    for (int c = 0; c < NC; ++c) mx = fmaxf(mx, lg[g * NC + c]);
    float sum = 0.f;
    for (int c = 0; c < NC; ++c) sum += expf(lg[g * NC + c] - mx);
    float lse = logf(sum);
    float ov[NC];
    float mx2 = -INFINITY;
    for (int c = 0; c < NC; ++c) {
      ov[c] = lg[g * NC + c] - mx - lse;
      outp[g * NC + c] = ov[c];
      mx2 = fmaxf(mx2, ov[c]);
    }
    float s2 = 0.f;
    for (int c = 0; c < NC; ++c) s2 += expf(ov[c] - mx2);
    for (int c = 0; c < NC; ++c) outp[NG * NC + g * NC + c] = expf(ov[c] - mx2) / s2;
  }
}

extern "C" void kernel_launch(void* const* d_in, const int* in_sizes, int n_in,
                              void* d_out, int out_size, void* d_ws, size_t ws_size,
                              hipStream_t stream) {
  const float* norm = (const float*)d_in[0];
  const float* pos  = (const float*)d_in[1];
  const float* x    = (const float*)d_in[2];
  const int* ei     = (const int*)d_in[3];   // int32! row0 = src, row1 = dst
  // d_in[4] = batch (int32, unused)
  const float* W1 = (const float*)d_in[5];
  const float* b1 = (const float*)d_in[6];
  const float* W2 = (const float*)d_in[7];
  const float* b2 = (const float*)d_in[8];
  const float* W3 = (const float*)d_in[9];
  const float* b3 = (const float*)d_in[10];
  const float* lw = (const float*)d_in[11];
  const float* lb = (const float*)d_in[12];
  float* outp = (float*)d_out;

  char* w = (char*)d_ws;
  size_t o = 0;
  auto alloc = [&](size_t bytes) -> void* {
    void* p = w + o;
    o = (o + bytes + 255) & ~(size_t)255;
    return p;
  };
  float* A    = (float*)alloc((size_t)NT * 128 * 4);  // t2 -> t3
  float* Bf   = (float*)alloc((size_t)NT * 128 * 4);  // h2
  float* T1   = (float*)alloc((size_t)NT * 64 * 4);   // t1
  float* xint = (float*)alloc((size_t)GS * 131 * 4);
  int* cols   = (int*)alloc((size_t)GS * KN * 4);
  int* cnt    = (int*)alloc((size_t)GS * 4);
  int* deg1   = (int*)alloc((size_t)NT * 4);
  int* off1   = (int*)alloc((size_t)(NT + 1) * 4);
  int* cur1   = (int*)alloc((size_t)NT * 4);
  int* el1    = (int*)alloc((size_t)NE * 4);
  int* deg2   = (int*)alloc((size_t)GS * 4);
  int* off2   = (int*)alloc((size_t)(GS + 1) * 4);
  int* cur2   = (int*)alloc((size_t)GS * 4);
  int* el2    = (int*)alloc((size_t)NE * 4);
  int* idxf   = (int*)alloc((size_t)GS * 4);
  float* qpos = (float*)alloc((size_t)GS * 3 * 4);
  int* mapv   = (int*)alloc((size_t)NT * 4);
  float* pooled = (float*)alloc((size_t)NG * 256 * 4);
  int* wctr   = (int*)alloc(128);

  hipMemsetAsync(deg1, 0, (size_t)NT * 4, stream);
  hipMemsetAsync(cur1, 0, (size_t)NT * 4, stream);
  hipMemsetAsync(deg2, 0, (size_t)GS * 4, stream);
  hipMemsetAsync(cur2, 0, (size_t)GS * 4, stream);
  hipMemsetAsync(mapv, 0xFF, (size_t)NT * 4, stream);  // -1
  hipMemsetAsync(pooled, 0, (size_t)NG * 256 * 4, stream);
  hipMemsetAsync(wctr, 0, 128, stream);

  // phase A (cooperative): fps ∥ {GCN layers 1-2}; workers exit early
  {
    void* ka[] = {(void*)&pos, (void*)&idxf, (void*)&qpos, (void*)&norm, (void*)&x,
                  (void*)&W1, (void*)&T1, (void*)&ei, (void*)&deg1,
                  (void*)&off1, (void*)&cur1, (void*)&el1,
                  (void*)&b1, (void*)&W2, (void*)&A, (void*)&b2, (void*)&Bf,
                  (void*)&wctr};
    hipLaunchCooperativeKernel((const void*)phaseA_kernel, dim3(8 + NWORK), dim3(256),
                               ka, 0, stream);
  }
  // radius (4 lanes/sample, fused mapset), pointconv with full TLP
  radius_kernel<<<256, 256, 0, stream>>>(pos, qpos, cols, cnt, idxf, mapv);
  pointconv_kernel<<<GS, 64, 0, stream>>>(Bf, pos, qpos, cols, cnt, xint);
  // feat3 (16 samples/block) + deg2
  post2_kernel<<<NF3B + NE / 256, 256, 0, stream>>>(xint, idxf, norm, pos, x, W3, A,
                                                    ei, mapv, deg2);
  scan_kernel<<<1, 1024, 0, stream>>>(deg2, off2, GS);
  fill2_kernel<<<NE / 256, 256, 0, stream>>>(ei, mapv, off2, cur2, el2);
  // layer 3 aggregation fused with global max-pool
  aggpool_kernel<<<GS, 256, 0, stream>>>(A, off2, el2, b3, pooled);
  head_kernel<<<1, 128, 0, stream>>>(pooled, lw, lb, outp);
}

// Round 14
// 1995.625 us; speedup vs baseline: 1.3659x; 1.0368x over previous
//
#include <hip/hip_runtime.h>
#include <hip/hip_bf16.h>

constexpr int NG   = 8;          // graphs
constexpr int NPG  = 4096;       // nodes per graph
constexpr int NT   = NG * NPG;   // 32768 total nodes
constexpr int NS   = 2048;       // fps samples per graph
constexpr int GS   = NG * NS;    // 16384
constexpr int KN   = 64;         // max neighbors
constexpr int NE   = NG * 65536; // 524288 edges
constexpr int EPG  = 65536;      // edges per graph (contiguous)
constexpr int NC   = 13;         // classes
constexpr int NWORK = 248;       // worker blocks in phaseA (blocks 8..255)
constexpr int SPB  = 16;         // samples per block in post2 feat3
constexpr int NF3B = GS / SPB;   // 1024 feat3 blocks

__device__ __forceinline__ float inp_val(const float* norm, const float* pos, const float* x,
                                         int node, int dim) {
  if (dim < 3) return norm[(size_t)node * 3 + dim];
  if (dim < 6) return pos[(size_t)node * 3 + (dim - 3)];
  return x[(size_t)node * 2 + (dim - 6)];
}

// agent-scope arrive-and-wait barrier among the NWORK worker blocks
__device__ __forceinline__ void wbar(int* ctrs, int k, int target) {
  __syncthreads();
  __threadfence();
  if (threadIdx.x == 0) {
    __hip_atomic_fetch_add(&ctrs[k], 1, __ATOMIC_RELEASE, __HIP_MEMORY_SCOPE_AGENT);
    while (__hip_atomic_load(&ctrs[k], __ATOMIC_ACQUIRE, __HIP_MEMORY_SCOPE_AGENT) < target)
      __builtin_amdgcn_s_sleep(16);
  }
  __syncthreads();
}

// ---- phase A (cooperative, 256 blocks x 256 thr) — unchanged r13 form ----
__global__ __launch_bounds__(256, 1) void phaseA_kernel(
    const float* __restrict__ pos, int* __restrict__ idxf, float* __restrict__ qpos,
    const float* __restrict__ norm, const float* __restrict__ x,
    const float* __restrict__ W1, float* __restrict__ t1,
    const int* __restrict__ ei, int* __restrict__ deg,
    int* __restrict__ off1, int* __restrict__ cur1, int* __restrict__ el1,
    const float* __restrict__ b1, const float* __restrict__ W2, float* __restrict__ t2,
    const float* __restrict__ b2, float* __restrict__ h2,
    int* __restrict__ wctr) {
  if (blockIdx.x >= 8) {
    const int wb = blockIdx.x - 8;
    const int sub = threadIdx.x >> 6;
    const int f = threadIdx.x & 63;
    __shared__ float wrow[4][80];
    __shared__ int sscan[256];
    for (int n0 = wb * 4; n0 < NT; n0 += NWORK * 4) {
      int n = n0 + sub;
      if (f < 8) wrow[sub][f] = inp_val(norm, pos, x, n, f);
      float acc = 0.f;
#pragma unroll
      for (int i = 0; i < 8; ++i) acc += wrow[sub][i] * W1[i * 64 + f];
      t1[(size_t)n * 64 + f] = acc;
    }
    for (int e = wb * 256 + threadIdx.x; e < NE; e += NWORK * 256)
      atomicAdd(&deg[ei[NE + e]], 1);
    wbar(wctr, 0, NWORK);
    if (wb == 0) {
      int t = threadIdx.x, base = t * 128, s = 0;
      for (int i = 0; i < 128; ++i) s += deg[base + i];
      sscan[t] = s;
      __syncthreads();
      for (int d = 1; d < 256; d <<= 1) {
        int v = (t >= d) ? sscan[t - d] : 0;
        __syncthreads();
        sscan[t] += v;
        __syncthreads();
      }
      int excl = (t == 0) ? 0 : sscan[t - 1];
      for (int i = 0; i < 128; ++i) { off1[base + i] = excl; excl += deg[base + i]; }
      if (t == 255) off1[NT] = sscan[255];
    }
    wbar(wctr, 1, NWORK);
    for (int e = wb * 256 + threadIdx.x; e < NE; e += NWORK * 256) {
      int sN = ei[e], dN = ei[NE + e];
      int p = off1[dN] + atomicAdd(&cur1[dN], 1);
      el1[p] = sN;
    }
    wbar(wctr, 2, NWORK);
    for (int n0 = wb * 4; n0 < NT; n0 += NWORK * 4) {
      int n = n0 + sub;
      int e0 = off1[n], e1 = off1[n + 1];
      float acc = 0.f;
      for (int j = e0; j < e1; ++j) acc += t1[(size_t)el1[j] * 64 + f];
      wrow[sub][f] = fmaxf(acc + b1[f], 0.f);
      if (f < 8) wrow[sub][64 + f] = inp_val(norm, pos, x, n, f);
      float a0 = 0.f, a1 = 0.f;
#pragma unroll 8
      for (int i = 0; i < 72; ++i) {
        float r = wrow[sub][i];
        a0 += r * W2[i * 128 + f];
        a1 += r * W2[i * 128 + 64 + f];
      }
      t2[(size_t)n * 128 + f] = a0;
      t2[(size_t)n * 128 + 64 + f] = a1;
    }
    wbar(wctr, 3, NWORK);
    {
      const int f2 = threadIdx.x & 127, sub2 = threadIdx.x >> 7;
      for (int n0 = wb * 2; n0 < NT; n0 += NWORK * 2) {
        int n = n0 + sub2;
        int e0 = off1[n], e1 = off1[n + 1];
        float acc = 0.f;
        for (int j = e0; j < e1; ++j) acc += t2[(size_t)el1[j] * 128 + f2];
        h2[(size_t)n * 128 + f2] = fmaxf(acc + b2[f2], 0.f);
      }
    }
    return;
  }
  // ================= FPS (unchanged) =================
  const int g = blockIdx.x;
  __shared__ float4 sq[2][4];
  __shared__ int sidx[2][4];
  __shared__ float4 qrec[NS];
  __shared__ int irec[NS];
  const float* pg = pos + (size_t)g * NPG * 3;
  const int tid = threadIdx.x;
  const int wave = tid >> 6, lane = tid & 63;
  const int p0 = tid * 16;

  float a[48];
  {
    const float4* pg4 = reinterpret_cast<const float4*>(pg + (size_t)p0 * 3);
#pragma unroll
    for (int j = 0; j < 12; ++j) {
      float4 t = pg4[j];
      a[4 * j + 0] = t.x; a[4 * j + 1] = t.y; a[4 * j + 2] = t.z; a[4 * j + 3] = t.w;
    }
  }
  float px[16], py[16], pz[16], mind[16];
#pragma unroll
  for (int i = 0; i < 16; ++i) {
    px[i] = a[3 * i]; py[i] = a[3 * i + 1]; pz[i] = a[3 * i + 2];
    mind[i] = __int_as_float(0x7f800000);
  }
  float cx = pg[0], cy = pg[1], cz = pg[2];
  int idx_sel = 0;

  for (int s = 0; s < NS; ++s) {
    if (tid == 0) { irec[s] = idx_sel; qrec[s] = make_float4(cx, cy, cz, 0.f); }
    float bestv = -1.f, bx = 0.f, by = 0.f, bz = 0.f;
    int bi = 0;
#pragma unroll
    for (int i = 0; i < 16; ++i) {
      float dx = __fsub_rn(px[i], cx);
      float dy = __fsub_rn(py[i], cy);
      float dz = __fsub_rn(pz[i], cz);
      float dd = __fadd_rn(__fadd_rn(__fmul_rn(dx, dx), __fmul_rn(dy, dy)), __fmul_rn(dz, dz));
      float nm = fminf(mind[i], dd);
      mind[i] = nm;
      bool gt = nm > bestv;
      bestv = gt ? nm : bestv;
      bx = gt ? px[i] : bx;
      by = gt ? py[i] : by;
      bz = gt ? pz[i] : bz;
      bi = gt ? i : bi;
    }
    float v = bestv;
    v = fmaxf(v, __int_as_float(__builtin_amdgcn_update_dpp(0, __float_as_int(v), 0x111, 0xF, 0xF, true)));
    v = fmaxf(v, __int_as_float(__builtin_amdgcn_update_dpp(0, __float_as_int(v), 0x112, 0xF, 0xF, true)));
    v = fmaxf(v, __int_as_float(__builtin_amdgcn_update_dpp(0, __float_as_int(v), 0x114, 0xF, 0xF, true)));
    v = fmaxf(v, __int_as_float(__builtin_amdgcn_update_dpp(0, __float_as_int(v), 0x118, 0xF, 0xF, true)));
    v = fmaxf(v, __int_as_float(__builtin_amdgcn_update_dpp(0, __float_as_int(v), 0x142, 0xF, 0xF, true)));
    v = fmaxf(v, __int_as_float(__builtin_amdgcn_update_dpp(0, __float_as_int(v), 0x143, 0xF, 0xF, true)));
    int maxbits = __builtin_amdgcn_readlane(__float_as_int(v), 63);
    float wavemax = __int_as_float(maxbits);
    unsigned long long ball = __ballot(bestv == wavemax);
    int winner = __ffsll(ball) - 1;
    int b = s & 1;
    if (lane == winner) {
      sq[b][wave] = make_float4(bx, by, bz, wavemax);
      sidx[b][wave] = p0 + bi;
    }
    __syncthreads();
    float4 q0 = sq[b][0], q1 = sq[b][1], q2 = sq[b][2], q3 = sq[b][3];
    float4 qs = q3;
    if (q2.w >= qs.w) qs = q2;
    if (q1.w >= qs.w) qs = q1;
    if (q0.w >= qs.w) qs = q0;
    cx = qs.x; cy = qs.y; cz = qs.z;
    if (tid == 0) {
      int i0 = sidx[b][0], i1 = sidx[b][1], i2 = sidx[b][2], i3 = sidx[b][3];
      float r = q3.w; int is = i3;
      if (q2.w >= r) { r = q2.w; is = i2; }
      if (q1.w >= r) { r = q1.w; is = i1; }
      if (q0.w >= r) { r = q0.w; is = i0; }
      idx_sel = is;
    }
  }
  __syncthreads();
  for (int j = tid; j < NS; j += 256) {
    idxf[g * NS + j] = g * NPG + irec[j];
    float4 q = qrec[j];
    size_t m = (size_t)(g * NS + j) * 3;
    qpos[m + 0] = q.x; qpos[m + 1] = q.y; qpos[m + 2] = q.z;
  }
}

// ---- radius: 4 lanes/sample stripe scan + mapset; XCD-pinned (graph = blk&7) ----
__global__ __launch_bounds__(256, 1) void radius_kernel(
    const float* __restrict__ pos, const float* __restrict__ qpos,
    int* __restrict__ cols, int* __restrict__ cnt,
    const int* __restrict__ idxf, int* __restrict__ mp) {
  __shared__ float spx[NPG], spy[NPG], spz[NPG];
  __shared__ int sbuf[KN][64][4];
  const int g = blockIdx.x & 7;          // XCD-pin: graph g -> XCD g (heuristic, perf-only)
  const int s0 = (blockIdx.x >> 3) * 64;
  const float* pgc = pos + (size_t)g * NPG * 3;
  for (int i = threadIdx.x; i < NPG * 3; i += 256) {
    float v = pgc[i]; int node = i / 3, cc = i - node * 3;
    if (cc == 0) spx[node] = v; else if (cc == 1) spy[node] = v; else spz[node] = v;
  }
  __syncthreads();
  const int group = threadIdx.x >> 2;
  const int j = threadIdx.x & 3;
  const int m = g * NS + s0 + group;
  if (j == 0) mp[idxf[m]] = m;
  const float qx = qpos[(size_t)m * 3], qy = qpos[(size_t)m * 3 + 1],
              qz = qpos[(size_t)m * 3 + 2];
  int c = 0;
  const int i0 = j * 1024;
  for (int i = i0; i < i0 + 1024; ++i) {
    float dx = __fsub_rn(spx[i], qx);
    float dy = __fsub_rn(spy[i], qy);
    float dz = __fsub_rn(spz[i], qz);
    float d2 = __fadd_rn(__fadd_rn(__fmul_rn(dx, dx), __fmul_rn(dy, dy)), __fmul_rn(dz, dz));
    if (d2 < 0.16f) {
      sbuf[c][group][j] = i;
      if (++c == KN) break;
    }
  }
  const int lbase = (threadIdx.x & 63) & ~3;
  int c0 = __shfl(c, lbase + 0), c1 = __shfl(c, lbase + 1),
      c2 = __shfl(c, lbase + 2), c3 = __shfl(c, lbase + 3);
  int pre = (j > 0 ? c0 : 0) + (j > 1 ? c1 : 0) + (j > 2 ? c2 : 0);
  int total = c0 + c1 + c2 + c3;
  if (j == 0) cnt[m] = total < KN ? total : KN;
  int take = KN - pre;
  take = take < 0 ? 0 : (take > c ? c : take);
  int* outp = cols + (size_t)m * KN + pre;
  for (int i = 0; i < take; ++i) outp[i] = sbuf[i][group][j];
}

// ---- PointConv: 4 samples/block, XCD-pinned so h2[graph] (2MB) is L2-local ----
__global__ __launch_bounds__(256) void pointconv_kernel(const float* __restrict__ h2,
                                                        const float* __restrict__ pos,
                                                        const float* __restrict__ qpos,
                                                        const int* __restrict__ cols,
                                                        const int* __restrict__ cnt,
                                                        float* __restrict__ xint) {
  const int g = blockIdx.x & 7;          // XCD-pin
  const int chunk = blockIdx.x >> 3;     // 0..511
  const int ss = threadIdx.x >> 6;       // 0..3
  const int t = threadIdx.x & 63;
  const int m = g * NS + chunk * 4 + ss;
  int n = cnt[m];
  const int* cl = cols + (size_t)m * KN;
  float m0 = -INFINITY, m1 = -INFINITY, mp = -INFINITY;
  for (int k = 0; k < n; ++k) {
    int c = cl[k];
    size_t base = (size_t)(g * NPG + c);
    m0 = fmaxf(m0, h2[base * 128 + t]);
    m1 = fmaxf(m1, h2[base * 128 + 64 + t]);
    if (t < 3) mp = fmaxf(mp, pos[base * 3 + t]);
  }
  float* xo = xint + (size_t)m * 131;
  xo[t] = m0;
  xo[64 + t] = m1;
  if (t < 3) xo[128 + t] = __fsub_rn(mp, qpos[(size_t)m * 3 + t]);
}

// ---- post2: feat3 (SPB samples/block) + deg2 (XCD-pinned edge blocks) ----
__global__ void post2_kernel(const float* __restrict__ xint, const int* __restrict__ idxf,
                             const float* __restrict__ norm, const float* __restrict__ pos,
                             const float* __restrict__ x, const float* __restrict__ W3,
                             float* __restrict__ t3,
                             const int* __restrict__ ei, const int* __restrict__ mp,
                             int* __restrict__ deg) {
  if (blockIdx.x >= NF3B) {
    int wb = blockIdx.x - NF3B;                       // 0..2047; NF3B%8==0 keeps XCD phase
    int eb = (wb & 7) * 256 + (wb >> 3);              // graph (wb&7) edges -> XCD (wb&7)
    int e = eb * 256 + threadIdx.x;
    int ns = mp[ei[e]], nd = mp[ei[NE + e]];
    if (ns >= 0 && nd >= 0) atomicAdd(&deg[nd], 1);
    return;
  }
  __shared__ float srow[SPB][140];
  const int m0 = blockIdx.x * SPB;
  for (int jj = threadIdx.x; jj < SPB * 139; jj += 256) {
    int sub = jj / 139, i = jj - sub * 139;
    int m = m0 + sub;
    srow[sub][i] = (i < 131) ? xint[(size_t)m * 131 + i]
                             : inp_val(norm, pos, x, idxf[m], i - 131);
  }
  __syncthreads();
  int f = threadIdx.x;
  float acc[SPB];
#pragma unroll
  for (int s = 0; s < SPB; ++s) acc[s] = 0.f;
#pragma unroll 4
  for (int i = 0; i < 139; ++i) {
    float wv = W3[i * 256 + f];
#pragma unroll
    for (int s = 0; s < SPB; ++s) acc[s] += srow[s][i] * wv;
  }
#pragma unroll
  for (int s = 0; s < SPB; ++s) t3[(size_t)(m0 + s) * 256 + f] = acc[s];
}

__global__ void fill2_kernel(const int* __restrict__ ei, const int* __restrict__ mp,
                             const int* __restrict__ off, int* __restrict__ cur,
                             int* __restrict__ el) {
  int b = blockIdx.x;                               // 2048 blocks
  int eb = (b & 7) * 256 + (b >> 3);                // XCD-pin per graph
  int e = eb * 256 + threadIdx.x;
  int ns = mp[ei[e]], nd = mp[ei[NE + e]];
  if (ns >= 0 && nd >= 0) {
    int p = off[nd] + atomicAdd(&cur[nd], 1);
    el[p] = ns;
  }
}

// single-block exclusive scan, n <= 32768, writes out[0..n]
__global__ __launch_bounds__(1024) void scan_kernel(const int* __restrict__ in,
                                                    int* __restrict__ out, int n) {
  __shared__ int ls[1024];
  int tid = threadIdx.x;
  int per = (n + 1023) >> 10;
  int base = tid * per;
  int s = 0;
  for (int i = 0; i < per; ++i) { int idx = base + i; if (idx < n) s += in[idx]; }
  ls[tid] = s;
  __syncthreads();
  for (int d = 1; d < 1024; d <<= 1) {
    int v = (tid >= d) ? ls[tid - d] : 0;
    __syncthreads();
    ls[tid] += v;
    __syncthreads();
  }
  int excl = (tid == 0) ? 0 : ls[tid - 1];
  for (int i = 0; i < per; ++i) {
    int idx = base + i;
    if (idx < n) { out[idx] = excl; excl += in[idx]; }
  }
  if (tid == 1023) out[n] = ls[1023];
}

// ---- agg3 + pool fused, XCD-pinned so t3[graph] (2MB) is L2-local ----
__global__ void aggpool_kernel(const float* __restrict__ t, const int* __restrict__ off,
                               const int* __restrict__ el, const float* __restrict__ b,
                               float* __restrict__ pooled) {
  int node = (blockIdx.x & 7) * 2048 + (blockIdx.x >> 3);  // graph (blk&7) -> XCD (blk&7)
  int f = threadIdx.x;
  int e0 = off[node], e1 = off[node + 1];
  float acc = 0.f;
  for (int j = e0; j < e1; ++j) acc += t[(size_t)el[j] * 256 + f];
  float val = fmaxf(acc + b[f], 0.f);
  atomicMax((int*)pooled + (node >> 11) * 256 + f, __float_as_int(val));
}

__global__ void head_kernel(const float* __restrict__ pooled, const float* __restrict__ lw,
                            const float* __restrict__ lb, float* __restrict__ outp) {
  __shared__ float lg[NG * NC];
  int t = threadIdx.x;
  if (t < NG * NC) {
    int g = t / NC, c = t % NC;
    float acc = lb[c];
    for (int k = 0; k < 256; ++k) acc += pooled[g * 256 + k] * lw[k * NC + c];
    lg[t] = acc;
  }
  __syncthreads();
  if (t < NG) {
    int g = t;
    float mx = -INFINITY;
    for (int c = 0; c < NC; ++c) mx = fmaxf(mx, lg[g * NC + c]);
    float sum = 0.f;
    for (int c = 0; c < NC; ++c) sum += expf(lg[g * NC + c] - mx);
    float lse = logf(sum);
    float ov[NC];
    float mx2 = -INFINITY;
    for (int c = 0; c < NC; ++c) {
      ov[c] = lg[g * NC + c] - mx - lse;
      outp[g * NC + c] = ov[c];
      mx2 = fmaxf(mx2, ov[c]);
    }
    float s2 = 0.f;
    for (int c = 0; c < NC; ++c) s2 += expf(ov[c] - mx2);
    for (int c = 0; c < NC; ++c) outp[NG * NC + g * NC + c] = expf(ov[c] - mx2) / s2;
  }
}

extern "C" void kernel_launch(void* const* d_in, const int* in_sizes, int n_in,
                              void* d_out, int out_size, void* d_ws, size_t ws_size,
                              hipStream_t stream) {
  const float* norm = (const float*)d_in[0];
  const float* pos  = (const float*)d_in[1];
  const float* x    = (const float*)d_in[2];
  const int* ei     = (const int*)d_in[3];   // int32! row0 = src, row1 = dst
  const float* W1 = (const float*)d_in[5];
  const float* b1 = (const float*)d_in[6];
  const float* W2 = (const float*)d_in[7];
  const float* b2 = (const float*)d_in[8];
  const float* W3 = (const float*)d_in[9];
  const float* b3 = (const float*)d_in[10];
  const float* lw = (const float*)d_in[11];
  const float* lb = (const float*)d_in[12];
  float* outp = (float*)d_out;

  char* w = (char*)d_ws;
  size_t o = 0;
  auto alloc = [&](size_t bytes) -> void* {
    void* p = w + o;
    o = (o + bytes + 255) & ~(size_t)255;
    return p;
  };
  float* A    = (float*)alloc((size_t)NT * 128 * 4);  // t2 -> t3
  float* Bf   = (float*)alloc((size_t)NT * 128 * 4);  // h2
  float* T1   = (float*)alloc((size_t)NT * 64 * 4);   // t1
  float* xint = (float*)alloc((size_t)GS * 131 * 4);
  int* cols   = (int*)alloc((size_t)GS * KN * 4);
  int* cnt    = (int*)alloc((size_t)GS * 4);
  int* deg1   = (int*)alloc((size_t)NT * 4);
  int* off1   = (int*)alloc((size_t)(NT + 1) * 4);
  int* cur1   = (int*)alloc((size_t)NT * 4);
  int* el1    = (int*)alloc((size_t)NE * 4);
  int* deg2   = (int*)alloc((size_t)GS * 4);
  int* off2   = (int*)alloc((size_t)(GS + 1) * 4);
  int* cur2   = (int*)alloc((size_t)GS * 4);
  int* el2    = (int*)alloc((size_t)NE * 4);
  int* idxf   = (int*)alloc((size_t)GS * 4);
  float* qpos = (float*)alloc((size_t)GS * 3 * 4);
  int* mapv   = (int*)alloc((size_t)NT * 4);
  float* pooled = (float*)alloc((size_t)NG * 256 * 4);
  int* wctr   = (int*)alloc(128);

  hipMemsetAsync(deg1, 0, (size_t)NT * 4, stream);
  hipMemsetAsync(cur1, 0, (size_t)NT * 4, stream);
  hipMemsetAsync(deg2, 0, (size_t)GS * 4, stream);
  hipMemsetAsync(cur2, 0, (size_t)GS * 4, stream);
  hipMemsetAsync(mapv, 0xFF, (size_t)NT * 4, stream);  // -1
  hipMemsetAsync(pooled, 0, (size_t)NG * 256 * 4, stream);
  hipMemsetAsync(wctr, 0, 128, stream);

  // phase A (cooperative): fps ∥ {GCN layers 1-2}; workers exit early
  {
    void* ka[] = {(void*)&pos, (void*)&idxf, (void*)&qpos, (void*)&norm, (void*)&x,
                  (void*)&W1, (void*)&T1, (void*)&ei, (void*)&deg1,
                  (void*)&off1, (void*)&cur1, (void*)&el1,
                  (void*)&b1, (void*)&W2, (void*)&A, (void*)&b2, (void*)&Bf,
                  (void*)&wctr};
    hipLaunchCooperativeKernel((const void*)phaseA_kernel, dim3(8 + NWORK), dim3(256),
                               ka, 0, stream);
  }
  // tail: all gather stages XCD-pinned per graph
  radius_kernel<<<256, 256, 0, stream>>>(pos, qpos, cols, cnt, idxf, mapv);
  pointconv_kernel<<<GS / 4, 256, 0, stream>>>(Bf, pos, qpos, cols, cnt, xint);
  post2_kernel<<<NF3B + NE / 256, 256, 0, stream>>>(xint, idxf, norm, pos, x, W3, A,
                                                    ei, mapv, deg2);
  scan_kernel<<<1, 1024, 0, stream>>>(deg2, off2, GS);
  fill2_kernel<<<NE / 256, 256, 0, stream>>>(ei, mapv, off2, cur2, el2);
  aggpool_kernel<<<GS, 256, 0, stream>>>(A, off2, el2, b3, pooled);
  head_kernel<<<1, 128, 0, stream>>>(pooled, lw, lb, outp);
}